// Round 3
// baseline (894.945 us; speedup 1.0000x reference)
//
#include <hip/hip_runtime.h>
#include <stdint.h>

#define B 8
#define NN 2000
#define EG 64000
#define FF 1024
#define DD 128
#define BK 32

typedef short short8 __attribute__((ext_vector_type(8)));
typedef float f32x4 __attribute__((ext_vector_type(4)));

__device__ __forceinline__ unsigned short f2bf(float f) {
    union { float f; unsigned int u; } v; v.f = f;
    unsigned int u = v.u;
    unsigned int r = u + 0x7FFFu + ((u >> 16) & 1u);
    return (unsigned short)(r >> 16);
}
__device__ __forceinline__ float leaky(float v) { return v >= 0.0f ? v : 0.01f * v; }

// unpack uint4 = 8 bf16 and fma into r[0..7] with weight w
__device__ __forceinline__ void acc8(float* __restrict__ r, float w, uint4 v) {
    union { unsigned int u; float f; } c;
    unsigned int u;
    u = v.x; c.u = u << 16; r[0] += w * c.f; c.u = u & 0xffff0000u; r[1] += w * c.f;
    u = v.y; c.u = u << 16; r[2] += w * c.f; c.u = u & 0xffff0000u; r[3] += w * c.f;
    u = v.z; c.u = u << 16; r[4] += w * c.f; c.u = u & 0xffff0000u; r[5] += w * c.f;
    u = v.w; c.u = u << 16; r[6] += w * c.f; c.u = u & 0xffff0000u; r[7] += w * c.f;
}

// ---------------- small utility kernels ----------------
__global__ void k_fillf(float* __restrict__ p, float v, int n) {
    int i = blockIdx.x * 256 + threadIdx.x;
    if (i < n) p[i] = v;
}

__global__ void k_degcount(const int* __restrict__ ei, float* __restrict__ deg) {
    int i = blockIdx.x * 256 + threadIdx.x;
    if (i >= B * EG) return;
    int b = i / EG, e = i - b * EG;
    int t = ei[b * 2 * EG + EG + e];
    atomicAdd(&deg[b * NN + t], 1.0f);
}

__global__ void k_dinv(const float* __restrict__ deg, float* __restrict__ dinv, int n) {
    int i = blockIdx.x * 256 + threadIdx.x;
    if (i < n) dinv[i] = rsqrtf(deg[i]);
}

// per-batch exclusive scan of in-degree -> CSR offsets (+cursor init)
__global__ void k_scan(const float* __restrict__ deg, int* __restrict__ csr_off,
                       int* __restrict__ cursor) {
    int b = blockIdx.x, t = threadIdx.x;
    __shared__ int part[256];
    int loc[8];
    int s = 0;
#pragma unroll
    for (int i = 0; i < 8; ++i) {
        int n = t * 8 + i;
        int c = (n < NN) ? ((int)deg[b * NN + n] - 1) : 0;
        loc[i] = s;
        s += c;
    }
    part[t] = s;
    __syncthreads();
    for (int off = 1; off < 256; off <<= 1) {
        int v = (t >= off) ? part[t - off] : 0;
        __syncthreads();
        part[t] += v;
        __syncthreads();
    }
    int base = part[t] - s;
#pragma unroll
    for (int i = 0; i < 8; ++i) {
        int n = t * 8 + i;
        if (n < NN) {
            int o = base + loc[i];
            csr_off[b * (NN + 1) + n] = o;
            cursor[b * NN + n] = o;
        }
    }
    if (t == 255) csr_off[b * (NN + 1) + NN] = part[255];
}

// fill CSR: packed (src, weight) per edge (dinv must be ready)
__global__ void k_fillcsr(const int* __restrict__ ei, int* __restrict__ cursor,
                          const float* __restrict__ dinv, int2* __restrict__ epk) {
    int i = blockIdx.x * 256 + threadIdx.x;
    if (i >= B * EG) return;
    int b = i / EG, e = i - b * EG;
    int s = ei[b * 2 * EG + e];
    int t = ei[b * 2 * EG + EG + e];
    int pos = atomicAdd(&cursor[b * NN + t], 1);
    int2 p;
    p.x = s;
    p.y = __float_as_int(dinv[b * NN + s] * dinv[b * NN + t]);
    epk[b * EG + pos] = p;
}

__global__ void k_convx(const float* __restrict__ x, unsigned short* __restrict__ xb, int n4) {
    int i = blockIdx.x * 256 + threadIdx.x;
    if (i >= n4) return;
    float4 v = ((const float4*)x)[i];
    ushort4 o;
    o.x = f2bf(v.x); o.y = f2bf(v.y); o.z = f2bf(v.z); o.w = f2bf(v.w);
    ((ushort4*)xb)[i] = o;
}

// transpose+convert Wg[F][F] fp32 -> wT[n][k] bf16
__global__ void k_wT(const float* __restrict__ Wg, unsigned short* __restrict__ wT) {
    __shared__ float tile[32][33];
    int tx = threadIdx.x, ty = threadIdx.y;  // 32 x 8
    int k0 = blockIdx.y * 32, n0 = blockIdx.x * 32;
#pragma unroll
    for (int r = 0; r < 4; ++r) {
        int row = ty + r * 8;
        tile[row][tx] = Wg[(k0 + row) * FF + n0 + tx];
    }
    __syncthreads();
#pragma unroll
    for (int r = 0; r < 4; ++r) {
        int row = ty + r * 8;
        wT[(n0 + row) * FF + k0 + tx] = f2bf(tile[tx][row]);
    }
}

// ---------------- bf16 MFMA GEMM (m97-style global_load_lds staging) ----------------
// H = A(16000x1024) * W, W given as wT[n][k]. Tile 128x128, BK=32.
// LDS rows UNPADDED (stride 32 elems = 64B): global_load_lds lands lane l at
// base + l*16B; mapping lane->(row l>>2, 16B-chunk l&3) makes that contiguous.
__launch_bounds__(256) __global__
void k_gemm(const unsigned short* __restrict__ Abf, const unsigned short* __restrict__ Bbf,
            unsigned short* __restrict__ Hbf) {
    __shared__ __align__(16) unsigned short As[128 * BK];
    __shared__ __align__(16) unsigned short Bs[128 * BK];
    int tid = threadIdx.x;
    int lane = tid & 63, wave = tid >> 6;
    int wr = wave >> 1, wc = wave & 1;
    int m0 = blockIdx.x * 128, n0 = blockIdx.y * 128;
    int q = lane >> 4, l15 = lane & 15;
    int lr = lane >> 2, lc = lane & 3;

    f32x4 acc[4][4];
#pragma unroll
    for (int i = 0; i < 4; ++i)
#pragma unroll
        for (int j = 0; j < 4; ++j) acc[i][j] = (f32x4){0.f, 0.f, 0.f, 0.f};

    for (int kt = 0; kt < 32; ++kt) {
        int kb = kt * BK;
#pragma unroll
        for (int p = 0; p < 2; ++p) {
            int rbase = p * 64 + wave * 16;      // wave-uniform
            int r = rbase + lr;                  // per-lane global row
            __builtin_amdgcn_global_load_lds(
                (const __attribute__((address_space(1))) unsigned int*)
                    &Abf[(size_t)(m0 + r) * FF + kb + lc * 8],
                (__attribute__((address_space(3))) unsigned int*)&As[rbase * BK],
                16, 0, 0);
            __builtin_amdgcn_global_load_lds(
                (const __attribute__((address_space(1))) unsigned int*)
                    &Bbf[(size_t)(n0 + r) * FF + kb + lc * 8],
                (__attribute__((address_space(3))) unsigned int*)&Bs[rbase * BK],
                16, 0, 0);
        }
        __syncthreads();
        short8 fa[4], fb[4];
#pragma unroll
        for (int i = 0; i < 4; ++i)
            fa[i] = *(const short8*)&As[(wr * 64 + i * 16 + l15) * BK + q * 8];
#pragma unroll
        for (int j = 0; j < 4; ++j)
            fb[j] = *(const short8*)&Bs[(wc * 64 + j * 16 + l15) * BK + q * 8];
#pragma unroll
        for (int i = 0; i < 4; ++i)
#pragma unroll
            for (int j = 0; j < 4; ++j)
                acc[i][j] = __builtin_amdgcn_mfma_f32_16x16x32_bf16(fa[i], fb[j], acc[i][j], 0, 0, 0);
        __syncthreads();
    }
#pragma unroll
    for (int i = 0; i < 4; ++i) {
#pragma unroll
        for (int j = 0; j < 4; ++j) {
            int n = n0 + wc * 64 + j * 16 + l15;
#pragma unroll
            for (int v = 0; v < 4; ++v) {
                int m = m0 + wr * 64 + i * 16 + q * 4 + v;
                Hbf[(size_t)m * FF + n] = f2bf(acc[i][j][v]);
            }
        }
    }
}

// ---------------- fused aggregation + bias + leaky + node-sum ----------------
// grid: 2000 blocks; batch = blk&7 (XCD-pinned), 8 nodes/block.
// 2 teams of 128 lanes; team handles 4 nodes serially; lane covers 8 feats (16B).
// Edge loop unrolled 8x: 8 independent row-gathers in flight per wave.
__launch_bounds__(256) __global__
void k_aggreduce(const unsigned short* __restrict__ Hbf, const int* __restrict__ csr_off,
                 const int2* __restrict__ epk, const float* __restrict__ dinv,
                 const float* __restrict__ bg, float* __restrict__ gsum) {
    int blk = blockIdx.x;
    int b = blk & 7;
    int chunk = blk >> 3;     // 0..249
    int tid = threadIdx.x;
    int team = tid >> 7;
    int lt = tid & 127;
    int f0 = lt * 8;
    int n0 = chunk * 8 + team * 4;
    const unsigned short* Hb = Hbf + (size_t)b * NN * FF;
    const int2* ep = epk + (size_t)b * EG;

    float bgv[8];
#pragma unroll
    for (int i = 0; i < 8; ++i) bgv[i] = bg[f0 + i];
    float bsum[8] = {0.f, 0.f, 0.f, 0.f, 0.f, 0.f, 0.f, 0.f};

    for (int nn = 0; nn < 4; ++nn) {
        int n = n0 + nn;
        float dn = dinv[b * NN + n];
        int beg = csr_off[b * (NN + 1) + n];
        int end = csr_off[b * (NN + 1) + n + 1];
        float racc[8] = {0.f, 0.f, 0.f, 0.f, 0.f, 0.f, 0.f, 0.f};
        {   // self-loop (weight 1/deg)
            uint4 sv = *(const uint4*)&Hb[(size_t)n * FF + f0];
            acc8(racc, dn * dn, sv);
        }
        int j = beg;
        for (; j + 8 <= end; j += 8) {
            int2 e[8];
#pragma unroll
            for (int i = 0; i < 8; ++i) e[i] = ep[j + i];
            uint4 v[8];
#pragma unroll
            for (int i = 0; i < 8; ++i)
                v[i] = *(const uint4*)&Hb[(size_t)e[i].x * FF + f0];
#pragma unroll
            for (int i = 0; i < 8; ++i) acc8(racc, __int_as_float(e[i].y), v[i]);
        }
        if (j + 4 <= end) {
            int2 e[4];
#pragma unroll
            for (int i = 0; i < 4; ++i) e[i] = ep[j + i];
            uint4 v[4];
#pragma unroll
            for (int i = 0; i < 4; ++i)
                v[i] = *(const uint4*)&Hb[(size_t)e[i].x * FF + f0];
#pragma unroll
            for (int i = 0; i < 4; ++i) acc8(racc, __int_as_float(e[i].y), v[i]);
            j += 4;
        }
        for (; j < end; ++j) {
            int2 e = ep[j];
            uint4 v = *(const uint4*)&Hb[(size_t)e.x * FF + f0];
            acc8(racc, __int_as_float(e.y), v);
        }
#pragma unroll
        for (int i = 0; i < 8; ++i) bsum[i] += leaky(racc[i] + bgv[i]);
    }

    // combine the two teams, then one atomic per lane of team 0
    __shared__ float red[128 * 8];
    if (team == 1) {
#pragma unroll
        for (int i = 0; i < 8; ++i) red[lt * 8 + i] = bsum[i];
    }
    __syncthreads();
    if (team == 0) {
#pragma unroll
        for (int i = 0; i < 8; ++i)
            atomicAdd(&gsum[b * FF + f0 + i], bsum[i] + red[lt * 8 + i]);
    }
}

// g[b,d] = leaky( (gsum[b,:]/N) @ Wf[:,d] + bf[d] )
__global__ void k_fc(const float* __restrict__ gsum, const float* __restrict__ Wf,
                     const float* __restrict__ bfv, float* __restrict__ g) {
    int b = blockIdx.x, d = threadIdx.x;  // 128 threads
    float acc = 0.f;
#pragma unroll 8
    for (int f = 0; f < FF; ++f) acc += gsum[b * FF + f] * Wf[f * DD + d];
    acc = acc * (1.0f / (float)NN) + bfv[d];
    g[b * DD + d] = leaky(acc);
}

__launch_bounds__(256) __global__
void k_head(const float* __restrict__ g, const float* __restrict__ W1, const float* __restrict__ b1,
            const float* __restrict__ W2, const float* __restrict__ b2,
            const float* __restrict__ Wo, const float* __restrict__ bo, float* __restrict__ out) {
    __shared__ float xc[8][256];
    __shared__ float l1[8][256];
    __shared__ float l2[8][64];
    int t = threadIdx.x;
#pragma unroll
    for (int i = 0; i < 8; ++i) {
        int idx = i * 256 + t;
        int b = idx >> 8, j = idx & 255;
        xc[b][j] = (j < DD) ? g[b * DD + j] : g[B * DD + b * DD + (j - DD)];
    }
    __syncthreads();
    {
        int j = t;
        float a[8];
#pragma unroll
        for (int b = 0; b < 8; ++b) a[b] = b1[j];
        for (int k = 0; k < 256; ++k) {
            float w = W1[k * 256 + j];
#pragma unroll
            for (int b = 0; b < 8; ++b) a[b] += xc[b][k] * w;
        }
#pragma unroll
        for (int b = 0; b < 8; ++b) l1[b][j] = leaky(a[b]);
    }
    __syncthreads();
    if (t < 64) {
        int j = t;
        float a[8];
#pragma unroll
        for (int b = 0; b < 8; ++b) a[b] = b2[j];
        for (int k = 0; k < 256; ++k) {
            float w = W2[k * 64 + j];
#pragma unroll
            for (int b = 0; b < 8; ++b) a[b] += l1[b][k] * w;
        }
#pragma unroll
        for (int b = 0; b < 8; ++b) l2[b][j] = leaky(a[b]);
    }
    __syncthreads();
    if (t < 8) {
        float a = bo[0];
        for (int k = 0; k < 64; ++k) a += l2[t][k] * Wo[k];
        out[t] = 1.0f / (1.0f + expf(-a));
    }
}

extern "C" void kernel_launch(void* const* d_in, const int* in_sizes, int n_in,
                              void* d_out, int out_size, void* d_ws, size_t ws_size,
                              hipStream_t stream) {
    const float* x1  = (const float*)d_in[0];
    const int*   ei1 = (const int*)d_in[1];
    const float* x2  = (const float*)d_in[2];
    const int*   ei2 = (const int*)d_in[3];
    const float* Wg1 = (const float*)d_in[4];
    const float* bg1 = (const float*)d_in[5];
    const float* Wf1 = (const float*)d_in[6];
    const float* bf1 = (const float*)d_in[7];
    const float* Wg2 = (const float*)d_in[8];
    const float* bg2 = (const float*)d_in[9];
    const float* Wf2 = (const float*)d_in[10];
    const float* bf2 = (const float*)d_in[11];
    const float* W1  = (const float*)d_in[12];
    const float* b1  = (const float*)d_in[13];
    const float* W2  = (const float*)d_in[14];
    const float* b2  = (const float*)d_in[15];
    const float* Wo  = (const float*)d_in[16];
    const float* bo  = (const float*)d_in[17];
    float* out = (float*)d_out;

    char* w = (char*)d_ws;
    auto alloc = [&](size_t bytes) {
        char* p = w;
        w += (bytes + 255) & ~(size_t)255;
        return p;
    };
    float* deg      = (float*)alloc((size_t)B * NN * 4);
    float* dinv     = (float*)alloc((size_t)B * NN * 4);
    int* csr_off    = (int*)alloc((size_t)B * (NN + 1) * 4);
    int* cursor     = (int*)alloc((size_t)B * NN * 4);
    int2* epk       = (int2*)alloc((size_t)B * EG * 8);
    unsigned short* xbf = (unsigned short*)alloc((size_t)B * NN * FF * 2);
    unsigned short* wT  = (unsigned short*)alloc((size_t)FF * FF * 2);
    unsigned short* hbf = (unsigned short*)alloc((size_t)B * NN * FF * 2);
    float* gsum     = (float*)alloc((size_t)2 * B * FF * 4);
    float* g12      = (float*)alloc((size_t)2 * B * DD * 4);

    k_fillf<<<(2 * B * FF + 255) / 256, 256, 0, stream>>>(gsum, 0.0f, 2 * B * FF);

    const float* xs[2]  = {x1, x2};
    const int*   eis[2] = {ei1, ei2};
    const float* Wgs[2] = {Wg1, Wg2};
    const float* bgs[2] = {bg1, bg2};
    const float* Wfs[2] = {Wf1, Wf2};
    const float* bfs[2] = {bf1, bf2};

    for (int br = 0; br < 2; ++br) {
        k_fillf<<<(B * NN + 255) / 256, 256, 0, stream>>>(deg, 1.0f, B * NN);
        k_degcount<<<(B * EG + 255) / 256, 256, 0, stream>>>(eis[br], deg);
        k_scan<<<B, 256, 0, stream>>>(deg, csr_off, cursor);
        k_dinv<<<(B * NN + 255) / 256, 256, 0, stream>>>(deg, dinv, B * NN);
        k_fillcsr<<<(B * EG + 255) / 256, 256, 0, stream>>>(eis[br], cursor, dinv, epk);
        k_convx<<<(B * NN * FF / 4 + 255) / 256, 256, 0, stream>>>(xs[br], xbf, B * NN * FF / 4);
        k_wT<<<dim3(32, 32), dim3(32, 8), 0, stream>>>(Wgs[br], wT);
        k_gemm<<<dim3(125, 8), 256, 0, stream>>>(xbf, wT, hbf);
        k_aggreduce<<<B * 250, 256, 0, stream>>>(hbf, csr_off, epk, dinv, bgs[br],
                                                 gsum + (size_t)br * B * FF);
        k_fc<<<B, DD, 0, stream>>>(gsum + (size_t)br * B * FF, Wfs[br], bfs[br],
                                   g12 + (size_t)br * B * DD);
    }
    k_head<<<1, 256, 0, stream>>>(g12, W1, b1, W2, b2, Wo, bo, out);
}

// Round 4
// 708.704 us; speedup vs baseline: 1.2628x; 1.2628x over previous
//
#include <hip/hip_runtime.h>
#include <stdint.h>

#define B 8
#define NN 2000
#define EG 64000
#define FF 1024
#define DD 128
#define BK 32
#define NCHUNK 125   // aggreduce chunks per graph (16 nodes each)

typedef short short8 __attribute__((ext_vector_type(8)));
typedef float f32x4 __attribute__((ext_vector_type(4)));

__device__ __forceinline__ unsigned short f2bf(float f) {
    union { float f; unsigned int u; } v; v.f = f;
    unsigned int u = v.u;
    unsigned int r = u + 0x7FFFu + ((u >> 16) & 1u);
    return (unsigned short)(r >> 16);
}
__device__ __forceinline__ float leaky(float v) { return v >= 0.0f ? v : 0.01f * v; }

// unpack uint4 = 8 bf16 and fma into r[0..7] with weight w
__device__ __forceinline__ void acc8(float* __restrict__ r, float w, uint4 v) {
    union { unsigned int u; float f; } c;
    unsigned int u;
    u = v.x; c.u = u << 16; r[0] += w * c.f; c.u = u & 0xffff0000u; r[1] += w * c.f;
    u = v.y; c.u = u << 16; r[2] += w * c.f; c.u = u & 0xffff0000u; r[3] += w * c.f;
    u = v.z; c.u = u << 16; r[4] += w * c.f; c.u = u & 0xffff0000u; r[5] += w * c.f;
    u = v.w; c.u = u << 16; r[6] += w * c.f; c.u = u & 0xffff0000u; r[7] += w * c.f;
}

// ---------------- prep kernels (batched over NG graphs) ----------------
__global__ void k_fillf(float* __restrict__ p, float v, int n) {
    int i = blockIdx.x * 256 + threadIdx.x;
    if (i < n) p[i] = v;
}

__global__ void k_degcount(const int* __restrict__ ei_a, const int* __restrict__ ei_b,
                           float* __restrict__ deg, int ng) {
    int i = blockIdx.x * 256 + threadIdx.x;
    if (i >= ng * EG) return;
    int g = i / EG, e = i - g * EG;
    const int* ei = (g < B) ? (ei_a + (size_t)g * 2 * EG) : (ei_b + (size_t)(g - B) * 2 * EG);
    int t = ei[EG + e];
    atomicAdd(&deg[g * NN + t], 1.0f);
}

// per-graph exclusive scan of in-degree -> CSR offsets, cursor init, dinv
__global__ void k_scan(const float* __restrict__ deg, int* __restrict__ csr_off,
                       int* __restrict__ cursor, float* __restrict__ dinv) {
    int g = blockIdx.x, t = threadIdx.x;
    __shared__ int part[256];
    int loc[8];
    int s = 0;
#pragma unroll
    for (int i = 0; i < 8; ++i) {
        int n = t * 8 + i;
        float dv = (n < NN) ? deg[g * NN + n] : 1.0f;
        if (n < NN) dinv[g * NN + n] = rsqrtf(dv);
        int c = (n < NN) ? ((int)dv - 1) : 0;
        loc[i] = s;
        s += c;
    }
    part[t] = s;
    __syncthreads();
    for (int off = 1; off < 256; off <<= 1) {
        int v = (t >= off) ? part[t - off] : 0;
        __syncthreads();
        part[t] += v;
        __syncthreads();
    }
    int base = part[t] - s;
#pragma unroll
    for (int i = 0; i < 8; ++i) {
        int n = t * 8 + i;
        if (n < NN) {
            int o = base + loc[i];
            csr_off[g * (NN + 1) + n] = o;
            cursor[g * NN + n] = o;
        }
    }
    if (t == 255) csr_off[g * (NN + 1) + NN] = part[255];
}

// fill CSR: packed (src, weight) per edge
__global__ void k_fillcsr(const int* __restrict__ ei_a, const int* __restrict__ ei_b,
                          int* __restrict__ cursor, const float* __restrict__ dinv,
                          int2* __restrict__ epk, int ng) {
    int i = blockIdx.x * 256 + threadIdx.x;
    if (i >= ng * EG) return;
    int g = i / EG, e = i - g * EG;
    const int* ei = (g < B) ? (ei_a + (size_t)g * 2 * EG) : (ei_b + (size_t)(g - B) * 2 * EG);
    int s = ei[e];
    int t = ei[EG + e];
    int pos = atomicAdd(&cursor[g * NN + t], 1);
    int2 p;
    p.x = s;
    p.y = __float_as_int(dinv[g * NN + s] * dinv[g * NN + t]);
    epk[(size_t)g * EG + pos] = p;
}

__global__ void k_convx(const float* __restrict__ x_a, const float* __restrict__ x_b,
                        unsigned short* __restrict__ xb, int half4, int total4) {
    int i = blockIdx.x * 256 + threadIdx.x;
    if (i >= total4) return;
    float4 v = (i < half4) ? ((const float4*)x_a)[i] : ((const float4*)x_b)[i - half4];
    ushort4 o;
    o.x = f2bf(v.x); o.y = f2bf(v.y); o.z = f2bf(v.z); o.w = f2bf(v.w);
    ((ushort4*)xb)[i] = o;
}

// transpose+convert Wg[F][F] fp32 -> wT[n][k] bf16; blockIdx.z selects weight
__global__ void k_wT(const float* __restrict__ Wg_a, const float* __restrict__ Wg_b,
                     unsigned short* __restrict__ wT) {
    __shared__ float tile[32][33];
    int tx = threadIdx.x, ty = threadIdx.y;  // 32 x 8
    int k0 = blockIdx.y * 32, n0 = blockIdx.x * 32;
    const float* Wg = blockIdx.z ? Wg_b : Wg_a;
    unsigned short* o = wT + (size_t)blockIdx.z * FF * FF;
#pragma unroll
    for (int r = 0; r < 4; ++r) {
        int row = ty + r * 8;
        tile[row][tx] = Wg[(k0 + row) * FF + n0 + tx];
    }
    __syncthreads();
#pragma unroll
    for (int r = 0; r < 4; ++r) {
        int row = ty + r * 8;
        o[(n0 + row) * FF + k0 + tx] = f2bf(tile[tx][row]);
    }
}

// ---------------- bf16 MFMA GEMM (global_load_lds staging) ----------------
// Rows [0, 125 tiles) use wTa; rows [125, 250) use wTb (batched 2-branch A).
__launch_bounds__(256) __global__
void k_gemm(const unsigned short* __restrict__ Abf, const unsigned short* __restrict__ wTa,
            const unsigned short* __restrict__ wTb, unsigned short* __restrict__ Hbf) {
    __shared__ __align__(16) unsigned short As[128 * BK];
    __shared__ __align__(16) unsigned short Bs[128 * BK];
    int tid = threadIdx.x;
    int lane = tid & 63, wave = tid >> 6;
    int wr = wave >> 1, wc = wave & 1;
    int m0 = blockIdx.x * 128, n0 = blockIdx.y * 128;
    const unsigned short* Bbf = (blockIdx.x >= 125) ? wTb : wTa;
    int q = lane >> 4, l15 = lane & 15;
    int lr = lane >> 2, lc = lane & 3;

    f32x4 acc[4][4];
#pragma unroll
    for (int i = 0; i < 4; ++i)
#pragma unroll
        for (int j = 0; j < 4; ++j) acc[i][j] = (f32x4){0.f, 0.f, 0.f, 0.f};

    for (int kt = 0; kt < 32; ++kt) {
        int kb = kt * BK;
#pragma unroll
        for (int p = 0; p < 2; ++p) {
            int rbase = p * 64 + wave * 16;      // wave-uniform
            int r = rbase + lr;                  // per-lane global row
            __builtin_amdgcn_global_load_lds(
                (const __attribute__((address_space(1))) unsigned int*)
                    &Abf[(size_t)(m0 + r) * FF + kb + lc * 8],
                (__attribute__((address_space(3))) unsigned int*)&As[rbase * BK],
                16, 0, 0);
            __builtin_amdgcn_global_load_lds(
                (const __attribute__((address_space(1))) unsigned int*)
                    &Bbf[(size_t)(n0 + r) * FF + kb + lc * 8],
                (__attribute__((address_space(3))) unsigned int*)&Bs[rbase * BK],
                16, 0, 0);
        }
        __syncthreads();
        short8 fa[4], fb[4];
#pragma unroll
        for (int i = 0; i < 4; ++i)
            fa[i] = *(const short8*)&As[(wr * 64 + i * 16 + l15) * BK + q * 8];
#pragma unroll
        for (int j = 0; j < 4; ++j)
            fb[j] = *(const short8*)&Bs[(wc * 64 + j * 16 + l15) * BK + q * 8];
#pragma unroll
        for (int i = 0; i < 4; ++i)
#pragma unroll
            for (int j = 0; j < 4; ++j)
                acc[i][j] = __builtin_amdgcn_mfma_f32_16x16x32_bf16(fa[i], fb[j], acc[i][j], 0, 0, 0);
        __syncthreads();
    }
#pragma unroll
    for (int i = 0; i < 4; ++i) {
#pragma unroll
        for (int j = 0; j < 4; ++j) {
            int n = n0 + wc * 64 + j * 16 + l15;
#pragma unroll
            for (int v = 0; v < 4; ++v) {
                int m = m0 + wr * 64 + i * 16 + q * 4 + v;
                Hbf[(size_t)m * FF + n] = f2bf(acc[i][j][v]);
            }
        }
    }
}

// ---------------- fused aggregation + bias + leaky + node-sum ----------------
// grid: NG*125 blocks; g = blk & (NG-1) so consecutive blocks round-robin XCDs
// by batch (g&7 = batch). 16 nodes/block, 2 teams x 128 lanes, unroll 4,
// plain partial stores (no atomics).
__launch_bounds__(256) __global__
void k_aggreduce(const unsigned short* __restrict__ Hbf, const int* __restrict__ csr_off,
                 const int2* __restrict__ epk, const float* __restrict__ dinv,
                 const float* __restrict__ bg_a, const float* __restrict__ bg_b,
                 float* __restrict__ part, int ngbits) {
    int blk = blockIdx.x;
    int g = blk & ((1 << ngbits) - 1);
    int chunk = blk >> ngbits;   // 0..124
    int tid = threadIdx.x;
    int team = tid >> 7;
    int lt = tid & 127;
    int f0 = lt * 8;
    int n0 = chunk * 16 + team * 8;
    const unsigned short* Hb = Hbf + (size_t)g * NN * FF;
    const int2* ep = epk + (size_t)g * EG;
    const float* bg = (g < B) ? bg_a : bg_b;

    float bgv[8];
#pragma unroll
    for (int i = 0; i < 8; ++i) bgv[i] = bg[f0 + i];
    float bsum[8] = {0.f, 0.f, 0.f, 0.f, 0.f, 0.f, 0.f, 0.f};

    for (int nn = 0; nn < 8; ++nn) {
        int n = n0 + nn;
        float dn = dinv[g * NN + n];
        int beg = csr_off[g * (NN + 1) + n];
        int end = csr_off[g * (NN + 1) + n + 1];
        float racc[8] = {0.f, 0.f, 0.f, 0.f, 0.f, 0.f, 0.f, 0.f};
        {   // self-loop (weight 1/deg)
            uint4 sv = *(const uint4*)&Hb[(size_t)n * FF + f0];
            acc8(racc, dn * dn, sv);
        }
        int j = beg;
        for (; j + 4 <= end; j += 4) {
            int2 e0 = ep[j], e1 = ep[j + 1], e2 = ep[j + 2], e3 = ep[j + 3];
            uint4 v0 = *(const uint4*)&Hb[(size_t)e0.x * FF + f0];
            uint4 v1 = *(const uint4*)&Hb[(size_t)e1.x * FF + f0];
            uint4 v2 = *(const uint4*)&Hb[(size_t)e2.x * FF + f0];
            uint4 v3 = *(const uint4*)&Hb[(size_t)e3.x * FF + f0];
            acc8(racc, __int_as_float(e0.y), v0);
            acc8(racc, __int_as_float(e1.y), v1);
            acc8(racc, __int_as_float(e2.y), v2);
            acc8(racc, __int_as_float(e3.y), v3);
        }
        for (; j < end; ++j) {
            int2 e = ep[j];
            uint4 v = *(const uint4*)&Hb[(size_t)e.x * FF + f0];
            acc8(racc, __int_as_float(e.y), v);
        }
#pragma unroll
        for (int i = 0; i < 8; ++i) bsum[i] += leaky(racc[i] + bgv[i]);
    }

    // combine the two teams, then plain store of block partial (no atomics)
    __shared__ float red[128 * 8];
    if (team == 1) {
#pragma unroll
        for (int i = 0; i < 8; ++i) red[lt * 8 + i] = bsum[i];
    }
    __syncthreads();
    if (team == 0) {
        float* o = part + ((size_t)g * NCHUNK + chunk) * FF + f0;
        float4 a, c;
        a.x = bsum[0] + red[lt * 8 + 0];
        a.y = bsum[1] + red[lt * 8 + 1];
        a.z = bsum[2] + red[lt * 8 + 2];
        a.w = bsum[3] + red[lt * 8 + 3];
        c.x = bsum[4] + red[lt * 8 + 4];
        c.y = bsum[5] + red[lt * 8 + 5];
        c.z = bsum[6] + red[lt * 8 + 6];
        c.w = bsum[7] + red[lt * 8 + 7];
        *(float4*)&o[0] = a;
        *(float4*)&o[4] = c;
    }
}

// reduce partials over chunks: gsum[g][f] = sum_c part[g][c][f]
__global__ void k_gsum(const float* __restrict__ part, float* __restrict__ gsum) {
    int g = blockIdx.x >> 2, quad = blockIdx.x & 3;
    int f = quad * 256 + threadIdx.x;
    float s = 0.f;
    const float* p = part + (size_t)g * NCHUNK * FF + f;
    for (int c = 0; c < NCHUNK; ++c) s += p[(size_t)c * FF];
    gsum[g * FF + f] = s;
}

// g12[g,d] = leaky( (gsum[g,:]/N) @ Wf[:,d] + bf[d] ), Wf per branch
__global__ void k_fc(const float* __restrict__ gsum, const float* __restrict__ Wf_a,
                     const float* __restrict__ bf_a, const float* __restrict__ Wf_b,
                     const float* __restrict__ bf_b, float* __restrict__ g12) {
    int g = blockIdx.x, d = threadIdx.x;  // 128 threads
    const float* Wf = (g < B) ? Wf_a : Wf_b;
    const float* bfv = (g < B) ? bf_a : bf_b;
    float acc = 0.f;
#pragma unroll 8
    for (int f = 0; f < FF; ++f) acc += gsum[g * FF + f] * Wf[f * DD + d];
    acc = acc * (1.0f / (float)NN) + bfv[d];
    g12[g * DD + d] = leaky(acc);
}

__launch_bounds__(256) __global__
void k_head(const float* __restrict__ g, const float* __restrict__ W1, const float* __restrict__ b1,
            const float* __restrict__ W2, const float* __restrict__ b2,
            const float* __restrict__ Wo, const float* __restrict__ bo, float* __restrict__ out) {
    __shared__ float xc[8][256];
    __shared__ float l1[8][256];
    __shared__ float l2[8][64];
    int t = threadIdx.x;
#pragma unroll
    for (int i = 0; i < 8; ++i) {
        int idx = i * 256 + t;
        int b = idx >> 8, j = idx & 255;
        xc[b][j] = (j < DD) ? g[b * DD + j] : g[B * DD + b * DD + (j - DD)];
    }
    __syncthreads();
    {
        int j = t;
        float a[8];
#pragma unroll
        for (int b = 0; b < 8; ++b) a[b] = b1[j];
        for (int k = 0; k < 256; ++k) {
            float w = W1[k * 256 + j];
#pragma unroll
            for (int b = 0; b < 8; ++b) a[b] += xc[b][k] * w;
        }
#pragma unroll
        for (int b = 0; b < 8; ++b) l1[b][j] = leaky(a[b]);
    }
    __syncthreads();
    if (t < 64) {
        int j = t;
        float a[8];
#pragma unroll
        for (int b = 0; b < 8; ++b) a[b] = b2[j];
        for (int k = 0; k < 256; ++k) {
            float w = W2[k * 64 + j];
#pragma unroll
            for (int b = 0; b < 8; ++b) a[b] += l1[b][k] * w;
        }
#pragma unroll
        for (int b = 0; b < 8; ++b) l2[b][j] = leaky(a[b]);
    }
    __syncthreads();
    if (t < 8) {
        float a = bo[0];
        for (int k = 0; k < 64; ++k) a += l2[t][k] * Wo[k];
        out[t] = 1.0f / (1.0f + expf(-a));
    }
}

extern "C" void kernel_launch(void* const* d_in, const int* in_sizes, int n_in,
                              void* d_out, int out_size, void* d_ws, size_t ws_size,
                              hipStream_t stream) {
    const float* x1  = (const float*)d_in[0];
    const int*   ei1 = (const int*)d_in[1];
    const float* x2  = (const float*)d_in[2];
    const int*   ei2 = (const int*)d_in[3];
    const float* Wg1 = (const float*)d_in[4];
    const float* bg1 = (const float*)d_in[5];
    const float* Wf1 = (const float*)d_in[6];
    const float* bf1 = (const float*)d_in[7];
    const float* Wg2 = (const float*)d_in[8];
    const float* bg2 = (const float*)d_in[9];
    const float* Wf2 = (const float*)d_in[10];
    const float* bf2 = (const float*)d_in[11];
    const float* W1  = (const float*)d_in[12];
    const float* b1  = (const float*)d_in[13];
    const float* W2  = (const float*)d_in[14];
    const float* b2  = (const float*)d_in[15];
    const float* Wo  = (const float*)d_in[16];
    const float* bo  = (const float*)d_in[17];
    float* out = (float*)d_out;

    // ---- batched (NG=16) workspace layout ----
    auto align = [](size_t v) { return (v + 255) & ~(size_t)255; };
    size_t need = 0;
    size_t o_deg  = need; need += align((size_t)16 * NN * 4);
    size_t o_dinv = need; need += align((size_t)16 * NN * 4);
    size_t o_csr  = need; need += align((size_t)16 * (NN + 1) * 4);
    size_t o_cur  = need; need += align((size_t)16 * NN * 4);
    size_t o_epk  = need; need += align((size_t)16 * EG * 8);
    size_t o_xbf  = need; need += align((size_t)16 * NN * FF * 2);
    size_t o_wT   = need; need += align((size_t)2 * FF * FF * 2);
    size_t o_hbf  = need; need += align((size_t)16 * NN * FF * 2);
    size_t o_part = need; need += align((size_t)16 * NCHUNK * FF * 4);
    size_t o_gsum = need; need += align((size_t)16 * FF * 4);
    size_t o_g12  = need; need += align((size_t)16 * DD * 4);

    char* w = (char*)d_ws;
    if (ws_size >= need) {
        // ---------- fully batched path: 11 dispatches ----------
        float* deg   = (float*)(w + o_deg);
        float* dinv  = (float*)(w + o_dinv);
        int* csr     = (int*)(w + o_csr);
        int* cur     = (int*)(w + o_cur);
        int2* epk    = (int2*)(w + o_epk);
        unsigned short* xbf = (unsigned short*)(w + o_xbf);
        unsigned short* wT  = (unsigned short*)(w + o_wT);
        unsigned short* hbf = (unsigned short*)(w + o_hbf);
        float* part  = (float*)(w + o_part);
        float* gsum  = (float*)(w + o_gsum);
        float* g12   = (float*)(w + o_g12);

        k_fillf<<<(16 * NN + 255) / 256, 256, 0, stream>>>(deg, 1.0f, 16 * NN);
        k_degcount<<<(16 * EG + 255) / 256, 256, 0, stream>>>(ei1, ei2, deg, 16);
        k_scan<<<16, 256, 0, stream>>>(deg, csr, cur, dinv);
        k_fillcsr<<<(16 * EG + 255) / 256, 256, 0, stream>>>(ei1, ei2, cur, dinv, epk, 16);
        int half4 = B * NN * FF / 4;
        k_convx<<<(2 * half4 + 255) / 256, 256, 0, stream>>>(x1, x2, xbf, half4, 2 * half4);
        k_wT<<<dim3(32, 32, 2), dim3(32, 8), 0, stream>>>(Wg1, Wg2, wT);
        k_gemm<<<dim3(250, 8), 256, 0, stream>>>(xbf, wT, wT + (size_t)FF * FF, hbf);
        k_aggreduce<<<16 * NCHUNK, 256, 0, stream>>>(hbf, csr, epk, dinv, bg1, bg2, part, 4);
        k_gsum<<<16 * 4, 256, 0, stream>>>(part, gsum);
        k_fc<<<16, DD, 0, stream>>>(gsum, Wf1, bf1, Wf2, bf2, g12);
        k_head<<<1, 256, 0, stream>>>(g12, W1, b1, W2, b2, Wo, bo, out);
    } else {
        // ---------- sequential fallback (NG=8 per branch) ----------
        size_t n2 = 0;
        size_t f_deg  = n2; n2 += align((size_t)B * NN * 4);
        size_t f_dinv = n2; n2 += align((size_t)B * NN * 4);
        size_t f_csr  = n2; n2 += align((size_t)B * (NN + 1) * 4);
        size_t f_cur  = n2; n2 += align((size_t)B * NN * 4);
        size_t f_epk  = n2; n2 += align((size_t)B * EG * 8);
        size_t f_xbf  = n2; n2 += align((size_t)B * NN * FF * 2);
        size_t f_wT   = n2; n2 += align((size_t)FF * FF * 2);
        size_t f_hbf  = n2; n2 += align((size_t)B * NN * FF * 2);
        size_t f_part = n2; n2 += align((size_t)B * NCHUNK * FF * 4);
        size_t f_gsum = n2; n2 += align((size_t)B * FF * 4);
        size_t f_g12  = n2; n2 += align((size_t)2 * B * DD * 4);

        float* deg   = (float*)(w + f_deg);
        float* dinv  = (float*)(w + f_dinv);
        int* csr     = (int*)(w + f_csr);
        int* cur     = (int*)(w + f_cur);
        int2* epk    = (int2*)(w + f_epk);
        unsigned short* xbf = (unsigned short*)(w + f_xbf);
        unsigned short* wT  = (unsigned short*)(w + f_wT);
        unsigned short* hbf = (unsigned short*)(w + f_hbf);
        float* part  = (float*)(w + f_part);
        float* gsum  = (float*)(w + f_gsum);
        float* g12   = (float*)(w + f_g12);

        const float* xs[2]  = {x1, x2};
        const int*   eis[2] = {ei1, ei2};
        const float* Wgs[2] = {Wg1, Wg2};
        const float* bgs[2] = {bg1, bg2};
        const float* Wfs[2] = {Wf1, Wf2};
        const float* bfs[2] = {bf1, bf2};

        for (int br = 0; br < 2; ++br) {
            k_fillf<<<(B * NN + 255) / 256, 256, 0, stream>>>(deg, 1.0f, B * NN);
            k_degcount<<<(B * EG + 255) / 256, 256, 0, stream>>>(eis[br], eis[br], deg, B);
            k_scan<<<B, 256, 0, stream>>>(deg, csr, cur, dinv);
            k_fillcsr<<<(B * EG + 255) / 256, 256, 0, stream>>>(eis[br], eis[br], cur, dinv, epk, B);
            int half4 = B * NN * FF / 4;
            k_convx<<<(half4 + 255) / 256, 256, 0, stream>>>(xs[br], xs[br], xbf, half4, half4);
            k_wT<<<dim3(32, 32, 1), dim3(32, 8), 0, stream>>>(Wgs[br], Wgs[br], wT);
            k_gemm<<<dim3(125, 8), 256, 0, stream>>>(xbf, wT, wT, hbf);
            k_aggreduce<<<B * NCHUNK, 256, 0, stream>>>(hbf, csr, epk, dinv, bgs[br], bgs[br], part, 3);
            k_gsum<<<B * 4, 256, 0, stream>>>(part, gsum);
            k_fc<<<B, DD, 0, stream>>>(gsum, Wfs[br], bfs[br], Wfs[br], bfs[br],
                                       g12 + (size_t)br * B * DD);
        }
        k_head<<<1, 256, 0, stream>>>(g12, W1, b1, W2, b2, Wo, bo, out);
    }
}

// Round 5
// 675.112 us; speedup vs baseline: 1.3256x; 1.0498x over previous
//
#include <hip/hip_runtime.h>
#include <stdint.h>

#define B 8
#define NN 2000
#define EG 64000
#define FF 1024
#define DD 128
#define BK 32
#define NCHUNK 125   // aggreduce chunks per graph (16 nodes each)

typedef short short8 __attribute__((ext_vector_type(8)));
typedef float f32x4 __attribute__((ext_vector_type(4)));

__device__ __forceinline__ unsigned short f2bf(float f) {
    union { float f; unsigned int u; } v; v.f = f;
    unsigned int u = v.u;
    unsigned int r = u + 0x7FFFu + ((u >> 16) & 1u);
    return (unsigned short)(r >> 16);
}
__device__ __forceinline__ float leaky(float v) { return v >= 0.0f ? v : 0.01f * v; }

// unpack uint4 = 8 bf16 and fma into r[0..7] with weight w
__device__ __forceinline__ void acc8(float* __restrict__ r, float w, uint4 v) {
    union { unsigned int u; float f; } c;
    unsigned int u;
    u = v.x; c.u = u << 16; r[0] += w * c.f; c.u = u & 0xffff0000u; r[1] += w * c.f;
    u = v.y; c.u = u << 16; r[2] += w * c.f; c.u = u & 0xffff0000u; r[3] += w * c.f;
    u = v.z; c.u = u << 16; r[4] += w * c.f; c.u = u & 0xffff0000u; r[5] += w * c.f;
    u = v.w; c.u = u << 16; r[6] += w * c.f; c.u = u & 0xffff0000u; r[7] += w * c.f;
}

// ---------------- prep kernels (batched over NG graphs) ----------------
__global__ void k_fillf(float* __restrict__ p, float v, int n) {
    int i = blockIdx.x * 256 + threadIdx.x;
    if (i < n) p[i] = v;
}

__global__ void k_degcount(const int* __restrict__ ei_a, const int* __restrict__ ei_b,
                           float* __restrict__ deg, int ng) {
    int i = blockIdx.x * 256 + threadIdx.x;
    if (i >= ng * EG) return;
    int g = i / EG, e = i - g * EG;
    const int* ei = (g < B) ? (ei_a + (size_t)g * 2 * EG) : (ei_b + (size_t)(g - B) * 2 * EG);
    int t = ei[EG + e];
    atomicAdd(&deg[g * NN + t], 1.0f);
}

// per-graph exclusive scan of in-degree -> CSR offsets, cursor init, dinv
__global__ void k_scan(const float* __restrict__ deg, int* __restrict__ csr_off,
                       int* __restrict__ cursor, float* __restrict__ dinv) {
    int g = blockIdx.x, t = threadIdx.x;
    __shared__ int part[256];
    int loc[8];
    int s = 0;
#pragma unroll
    for (int i = 0; i < 8; ++i) {
        int n = t * 8 + i;
        float dv = (n < NN) ? deg[g * NN + n] : 1.0f;
        if (n < NN) dinv[g * NN + n] = rsqrtf(dv);
        int c = (n < NN) ? ((int)dv - 1) : 0;
        loc[i] = s;
        s += c;
    }
    part[t] = s;
    __syncthreads();
    for (int off = 1; off < 256; off <<= 1) {
        int v = (t >= off) ? part[t - off] : 0;
        __syncthreads();
        part[t] += v;
        __syncthreads();
    }
    int base = part[t] - s;
#pragma unroll
    for (int i = 0; i < 8; ++i) {
        int n = t * 8 + i;
        if (n < NN) {
            int o = base + loc[i];
            csr_off[g * (NN + 1) + n] = o;
            cursor[g * NN + n] = o;
        }
    }
    if (t == 255) csr_off[g * (NN + 1) + NN] = part[255];
}

// fill CSR: packed (src, weight) per edge
__global__ void k_fillcsr(const int* __restrict__ ei_a, const int* __restrict__ ei_b,
                          int* __restrict__ cursor, const float* __restrict__ dinv,
                          int2* __restrict__ epk, int ng) {
    int i = blockIdx.x * 256 + threadIdx.x;
    if (i >= ng * EG) return;
    int g = i / EG, e = i - g * EG;
    const int* ei = (g < B) ? (ei_a + (size_t)g * 2 * EG) : (ei_b + (size_t)(g - B) * 2 * EG);
    int s = ei[e];
    int t = ei[EG + e];
    int pos = atomicAdd(&cursor[g * NN + t], 1);
    int2 p;
    p.x = s;
    p.y = __float_as_int(dinv[g * NN + s] * dinv[g * NN + t]);
    epk[(size_t)g * EG + pos] = p;
}

__global__ void k_convx(const float* __restrict__ x_a, const float* __restrict__ x_b,
                        unsigned short* __restrict__ xb, int half4, int total4) {
    int i = blockIdx.x * 256 + threadIdx.x;
    if (i >= total4) return;
    float4 v = (i < half4) ? ((const float4*)x_a)[i] : ((const float4*)x_b)[i - half4];
    ushort4 o;
    o.x = f2bf(v.x); o.y = f2bf(v.y); o.z = f2bf(v.z); o.w = f2bf(v.w);
    ((ushort4*)xb)[i] = o;
}

// transpose+convert Wg[F][F] fp32 -> wT[n][k] bf16; blockIdx.z selects weight
__global__ void k_wT(const float* __restrict__ Wg_a, const float* __restrict__ Wg_b,
                     unsigned short* __restrict__ wT) {
    __shared__ float tile[32][33];
    int tx = threadIdx.x, ty = threadIdx.y;  // 32 x 8
    int k0 = blockIdx.y * 32, n0 = blockIdx.x * 32;
    const float* Wg = blockIdx.z ? Wg_b : Wg_a;
    unsigned short* o = wT + (size_t)blockIdx.z * FF * FF;
#pragma unroll
    for (int r = 0; r < 4; ++r) {
        int row = ty + r * 8;
        tile[row][tx] = Wg[(k0 + row) * FF + n0 + tx];
    }
    __syncthreads();
#pragma unroll
    for (int r = 0; r < 4; ++r) {
        int row = ty + r * 8;
        o[(n0 + row) * FF + k0 + tx] = f2bf(tile[tx][row]);
    }
}

// ---------------- bf16 MFMA GEMM (global_load_lds staging) ----------------
// Block remap for L2 locality: blk bits [2:0]=XCD slot (part of m-tile),
// [5:3]=n-tile, [10:6]=m-group. Each XCD works through all 8 n-tiles of its
// own m-tiles => A tile stays in that XCD's L2 across n-phases.
// m-tiles >= 125 use wTb (branch 2 rows of the batched A).
__launch_bounds__(256) __global__
void k_gemm(const unsigned short* __restrict__ Abf, const unsigned short* __restrict__ wTa,
            const unsigned short* __restrict__ wTb, unsigned short* __restrict__ Hbf,
            int mtiles) {
    int blk = blockIdx.x;
    int mt = ((blk >> 6) << 3) | (blk & 7);
    int nt = (blk >> 3) & 7;
    if (mt >= mtiles) return;
    int m0 = mt * 128, n0 = nt * 128;
    const unsigned short* Bbf = (mt >= 125) ? wTb : wTa;

    __shared__ __align__(16) unsigned short As[128 * BK];
    __shared__ __align__(16) unsigned short Bs[128 * BK];
    int tid = threadIdx.x;
    int lane = tid & 63, wave = tid >> 6;
    int wr = wave >> 1, wc = wave & 1;
    int q = lane >> 4, l15 = lane & 15;
    int lr = lane >> 2, lc = lane & 3;

    f32x4 acc[4][4];
#pragma unroll
    for (int i = 0; i < 4; ++i)
#pragma unroll
        for (int j = 0; j < 4; ++j) acc[i][j] = (f32x4){0.f, 0.f, 0.f, 0.f};

    for (int kt = 0; kt < 32; ++kt) {
        int kb = kt * BK;
#pragma unroll
        for (int p = 0; p < 2; ++p) {
            int rbase = p * 64 + wave * 16;      // wave-uniform
            int r = rbase + lr;                  // per-lane global row
            __builtin_amdgcn_global_load_lds(
                (const __attribute__((address_space(1))) unsigned int*)
                    &Abf[(size_t)(m0 + r) * FF + kb + lc * 8],
                (__attribute__((address_space(3))) unsigned int*)&As[rbase * BK],
                16, 0, 0);
            __builtin_amdgcn_global_load_lds(
                (const __attribute__((address_space(1))) unsigned int*)
                    &Bbf[(size_t)(n0 + r) * FF + kb + lc * 8],
                (__attribute__((address_space(3))) unsigned int*)&Bs[rbase * BK],
                16, 0, 0);
        }
        __syncthreads();
        short8 fa[4], fb[4];
#pragma unroll
        for (int i = 0; i < 4; ++i)
            fa[i] = *(const short8*)&As[(wr * 64 + i * 16 + l15) * BK + q * 8];
#pragma unroll
        for (int j = 0; j < 4; ++j)
            fb[j] = *(const short8*)&Bs[(wc * 64 + j * 16 + l15) * BK + q * 8];
#pragma unroll
        for (int i = 0; i < 4; ++i)
#pragma unroll
            for (int j = 0; j < 4; ++j)
                acc[i][j] = __builtin_amdgcn_mfma_f32_16x16x32_bf16(fa[i], fb[j], acc[i][j], 0, 0, 0);
        __syncthreads();
    }
#pragma unroll
    for (int i = 0; i < 4; ++i) {
#pragma unroll
        for (int j = 0; j < 4; ++j) {
            int n = n0 + wc * 64 + j * 16 + l15;
#pragma unroll
            for (int v = 0; v < 4; ++v) {
                int m = m0 + wr * 64 + i * 16 + q * 4 + v;
                Hbf[(size_t)m * FF + n] = f2bf(acc[i][j][v]);
            }
        }
    }
}

// ---------------- fused aggregation + bias + leaky + node-sum ----------------
// Phased XCD pinning: blk < half -> graph blk&7 (XCD blk&7), blk >= half ->
// graph 8+(blk&7). Steady-state each XCD's L2 holds exactly one graph's H.
__launch_bounds__(256) __global__
void k_aggreduce(const unsigned short* __restrict__ Hbf, const int* __restrict__ csr_off,
                 const int2* __restrict__ epk, const float* __restrict__ dinv,
                 const float* __restrict__ bg_a, const float* __restrict__ bg_b,
                 float* __restrict__ part, int half) {
    int blk = blockIdx.x;
    int phase = (blk >= half);
    int bp = blk - phase * half;
    int g = phase * 8 + (bp & 7);
    int chunk = bp >> 3;         // 0..124
    int tid = threadIdx.x;
    int team = tid >> 7;
    int lt = tid & 127;
    int f0 = lt * 8;
    int n0 = chunk * 16 + team * 8;
    const unsigned short* Hb = Hbf + (size_t)g * NN * FF;
    const int2* ep = epk + (size_t)g * EG;
    const float* bg = (g < B) ? bg_a : bg_b;

    float bgv[8];
#pragma unroll
    for (int i = 0; i < 8; ++i) bgv[i] = bg[f0 + i];
    float bsum[8] = {0.f, 0.f, 0.f, 0.f, 0.f, 0.f, 0.f, 0.f};

    for (int nn = 0; nn < 8; ++nn) {
        int n = n0 + nn;
        float dn = dinv[g * NN + n];
        int beg = csr_off[g * (NN + 1) + n];
        int end = csr_off[g * (NN + 1) + n + 1];
        float racc[8] = {0.f, 0.f, 0.f, 0.f, 0.f, 0.f, 0.f, 0.f};
        {   // self-loop (weight 1/deg)
            uint4 sv = *(const uint4*)&Hb[(size_t)n * FF + f0];
            acc8(racc, dn * dn, sv);
        }
        int j = beg;
        for (; j + 4 <= end; j += 4) {
            int2 e0 = ep[j], e1 = ep[j + 1], e2 = ep[j + 2], e3 = ep[j + 3];
            uint4 v0 = *(const uint4*)&Hb[(size_t)e0.x * FF + f0];
            uint4 v1 = *(const uint4*)&Hb[(size_t)e1.x * FF + f0];
            uint4 v2 = *(const uint4*)&Hb[(size_t)e2.x * FF + f0];
            uint4 v3 = *(const uint4*)&Hb[(size_t)e3.x * FF + f0];
            acc8(racc, __int_as_float(e0.y), v0);
            acc8(racc, __int_as_float(e1.y), v1);
            acc8(racc, __int_as_float(e2.y), v2);
            acc8(racc, __int_as_float(e3.y), v3);
        }
        for (; j < end; ++j) {
            int2 e = ep[j];
            uint4 v = *(const uint4*)&Hb[(size_t)e.x * FF + f0];
            acc8(racc, __int_as_float(e.y), v);
        }
#pragma unroll
        for (int i = 0; i < 8; ++i) bsum[i] += leaky(racc[i] + bgv[i]);
    }

    // combine the two teams, then plain store of block partial (no atomics)
    __shared__ float red[128 * 8];
    if (team == 1) {
#pragma unroll
        for (int i = 0; i < 8; ++i) red[lt * 8 + i] = bsum[i];
    }
    __syncthreads();
    if (team == 0) {
        float* o = part + ((size_t)g * NCHUNK + chunk) * FF + f0;
        float4 a, c;
        a.x = bsum[0] + red[lt * 8 + 0];
        a.y = bsum[1] + red[lt * 8 + 1];
        a.z = bsum[2] + red[lt * 8 + 2];
        a.w = bsum[3] + red[lt * 8 + 3];
        c.x = bsum[4] + red[lt * 8 + 4];
        c.y = bsum[5] + red[lt * 8 + 5];
        c.z = bsum[6] + red[lt * 8 + 6];
        c.w = bsum[7] + red[lt * 8 + 7];
        *(float4*)&o[0] = a;
        *(float4*)&o[4] = c;
    }
}

// reduce partials over chunks: gsum[g][f] = sum_c part[g][c][f]
__global__ void k_gsum(const float* __restrict__ part, float* __restrict__ gsum) {
    int g = blockIdx.x >> 2, quad = blockIdx.x & 3;
    int f = quad * 256 + threadIdx.x;
    float s = 0.f;
    const float* p = part + (size_t)g * NCHUNK * FF + f;
    for (int c = 0; c < NCHUNK; ++c) s += p[(size_t)c * FF];
    gsum[g * FF + f] = s;
}

// g12[g,d] = leaky( (gsum[g,:]/N) @ Wf[:,d] + bf[d] ), Wf per branch
__global__ void k_fc(const float* __restrict__ gsum, const float* __restrict__ Wf_a,
                     const float* __restrict__ bf_a, const float* __restrict__ Wf_b,
                     const float* __restrict__ bf_b, float* __restrict__ g12) {
    int g = blockIdx.x, d = threadIdx.x;  // 128 threads
    const float* Wf = (g < B) ? Wf_a : Wf_b;
    const float* bfv = (g < B) ? bf_a : bf_b;
    float acc = 0.f;
#pragma unroll 8
    for (int f = 0; f < FF; ++f) acc += gsum[g * FF + f] * Wf[f * DD + d];
    acc = acc * (1.0f / (float)NN) + bfv[d];
    g12[g * DD + d] = leaky(acc);
}

__launch_bounds__(256) __global__
void k_head(const float* __restrict__ g, const float* __restrict__ W1, const float* __restrict__ b1,
            const float* __restrict__ W2, const float* __restrict__ b2,
            const float* __restrict__ Wo, const float* __restrict__ bo, float* __restrict__ out) {
    __shared__ float xc[8][256];
    __shared__ float l1[8][256];
    __shared__ float l2[8][64];
    int t = threadIdx.x;
#pragma unroll
    for (int i = 0; i < 8; ++i) {
        int idx = i * 256 + t;
        int b = idx >> 8, j = idx & 255;
        xc[b][j] = (j < DD) ? g[b * DD + j] : g[B * DD + b * DD + (j - DD)];
    }
    __syncthreads();
    {
        int j = t;
        float a[8];
#pragma unroll
        for (int b = 0; b < 8; ++b) a[b] = b1[j];
        for (int k = 0; k < 256; ++k) {
            float w = W1[k * 256 + j];
#pragma unroll
            for (int b = 0; b < 8; ++b) a[b] += xc[b][k] * w;
        }
#pragma unroll
        for (int b = 0; b < 8; ++b) l1[b][j] = leaky(a[b]);
    }
    __syncthreads();
    if (t < 64) {
        int j = t;
        float a[8];
#pragma unroll
        for (int b = 0; b < 8; ++b) a[b] = b2[j];
        for (int k = 0; k < 256; ++k) {
            float w = W2[k * 64 + j];
#pragma unroll
            for (int b = 0; b < 8; ++b) a[b] += l1[b][k] * w;
        }
#pragma unroll
        for (int b = 0; b < 8; ++b) l2[b][j] = leaky(a[b]);
    }
    __syncthreads();
    if (t < 8) {
        float a = bo[0];
        for (int k = 0; k < 64; ++k) a += l2[t][k] * Wo[k];
        out[t] = 1.0f / (1.0f + expf(-a));
    }
}

extern "C" void kernel_launch(void* const* d_in, const int* in_sizes, int n_in,
                              void* d_out, int out_size, void* d_ws, size_t ws_size,
                              hipStream_t stream) {
    const float* x1  = (const float*)d_in[0];
    const int*   ei1 = (const int*)d_in[1];
    const float* x2  = (const float*)d_in[2];
    const int*   ei2 = (const int*)d_in[3];
    const float* Wg1 = (const float*)d_in[4];
    const float* bg1 = (const float*)d_in[5];
    const float* Wf1 = (const float*)d_in[6];
    const float* bf1 = (const float*)d_in[7];
    const float* Wg2 = (const float*)d_in[8];
    const float* bg2 = (const float*)d_in[9];
    const float* Wf2 = (const float*)d_in[10];
    const float* bf2 = (const float*)d_in[11];
    const float* W1  = (const float*)d_in[12];
    const float* b1  = (const float*)d_in[13];
    const float* W2  = (const float*)d_in[14];
    const float* b2  = (const float*)d_in[15];
    const float* Wo  = (const float*)d_in[16];
    const float* bo  = (const float*)d_in[17];
    float* out = (float*)d_out;

    // ---- batched (NG=16) workspace layout ----
    auto align = [](size_t v) { return (v + 255) & ~(size_t)255; };
    size_t need = 0;
    size_t o_deg  = need; need += align((size_t)16 * NN * 4);
    size_t o_dinv = need; need += align((size_t)16 * NN * 4);
    size_t o_csr  = need; need += align((size_t)16 * (NN + 1) * 4);
    size_t o_cur  = need; need += align((size_t)16 * NN * 4);
    size_t o_epk  = need; need += align((size_t)16 * EG * 8);
    size_t o_xbf  = need; need += align((size_t)16 * NN * FF * 2);
    size_t o_wT   = need; need += align((size_t)2 * FF * FF * 2);
    size_t o_hbf  = need; need += align((size_t)16 * NN * FF * 2);
    size_t o_part = need; need += align((size_t)16 * NCHUNK * FF * 4);
    size_t o_gsum = need; need += align((size_t)16 * FF * 4);
    size_t o_g12  = need; need += align((size_t)16 * DD * 4);

    char* w = (char*)d_ws;
    if (ws_size >= need) {
        // ---------- fully batched path: 11 dispatches ----------
        float* deg   = (float*)(w + o_deg);
        float* dinv  = (float*)(w + o_dinv);
        int* csr     = (int*)(w + o_csr);
        int* cur     = (int*)(w + o_cur);
        int2* epk    = (int2*)(w + o_epk);
        unsigned short* xbf = (unsigned short*)(w + o_xbf);
        unsigned short* wT  = (unsigned short*)(w + o_wT);
        unsigned short* hbf = (unsigned short*)(w + o_hbf);
        float* part  = (float*)(w + o_part);
        float* gsum  = (float*)(w + o_gsum);
        float* g12   = (float*)(w + o_g12);

        k_fillf<<<(16 * NN + 255) / 256, 256, 0, stream>>>(deg, 1.0f, 16 * NN);
        k_degcount<<<(16 * EG + 255) / 256, 256, 0, stream>>>(ei1, ei2, deg, 16);
        k_scan<<<16, 256, 0, stream>>>(deg, csr, cur, dinv);
        k_fillcsr<<<(16 * EG + 255) / 256, 256, 0, stream>>>(ei1, ei2, cur, dinv, epk, 16);
        int half4 = B * NN * FF / 4;
        k_convx<<<(2 * half4 + 255) / 256, 256, 0, stream>>>(x1, x2, xbf, half4, 2 * half4);
        k_wT<<<dim3(32, 32, 2), dim3(32, 8), 0, stream>>>(Wg1, Wg2, wT);
        k_gemm<<<2048, 256, 0, stream>>>(xbf, wT, wT + (size_t)FF * FF, hbf, 250);
        k_aggreduce<<<2000, 256, 0, stream>>>(hbf, csr, epk, dinv, bg1, bg2, part, 1000);
        k_gsum<<<16 * 4, 256, 0, stream>>>(part, gsum);
        k_fc<<<16, DD, 0, stream>>>(gsum, Wf1, bf1, Wf2, bf2, g12);
        k_head<<<1, 256, 0, stream>>>(g12, W1, b1, W2, b2, Wo, bo, out);
    } else {
        // ---------- sequential fallback (NG=8 per branch) ----------
        size_t n2 = 0;
        size_t f_deg  = n2; n2 += align((size_t)B * NN * 4);
        size_t f_dinv = n2; n2 += align((size_t)B * NN * 4);
        size_t f_csr  = n2; n2 += align((size_t)B * (NN + 1) * 4);
        size_t f_cur  = n2; n2 += align((size_t)B * NN * 4);
        size_t f_epk  = n2; n2 += align((size_t)B * EG * 8);
        size_t f_xbf  = n2; n2 += align((size_t)B * NN * FF * 2);
        size_t f_wT   = n2; n2 += align((size_t)FF * FF * 2);
        size_t f_hbf  = n2; n2 += align((size_t)B * NN * FF * 2);
        size_t f_part = n2; n2 += align((size_t)B * NCHUNK * FF * 4);
        size_t f_gsum = n2; n2 += align((size_t)B * FF * 4);
        size_t f_g12  = n2; n2 += align((size_t)2 * B * DD * 4);

        float* deg   = (float*)(w + f_deg);
        float* dinv  = (float*)(w + f_dinv);
        int* csr     = (int*)(w + f_csr);
        int* cur     = (int*)(w + f_cur);
        int2* epk    = (int2*)(w + f_epk);
        unsigned short* xbf = (unsigned short*)(w + f_xbf);
        unsigned short* wT  = (unsigned short*)(w + f_wT);
        unsigned short* hbf = (unsigned short*)(w + f_hbf);
        float* part  = (float*)(w + f_part);
        float* gsum  = (float*)(w + f_gsum);
        float* g12   = (float*)(w + f_g12);

        const float* xs[2]  = {x1, x2};
        const int*   eis[2] = {ei1, ei2};
        const float* Wgs[2] = {Wg1, Wg2};
        const float* bgs[2] = {bg1, bg2};
        const float* Wfs[2] = {Wf1, Wf2};
        const float* bfs[2] = {bf1, bf2};

        for (int br = 0; br < 2; ++br) {
            k_fillf<<<(B * NN + 255) / 256, 256, 0, stream>>>(deg, 1.0f, B * NN);
            k_degcount<<<(B * EG + 255) / 256, 256, 0, stream>>>(eis[br], eis[br], deg, B);
            k_scan<<<B, 256, 0, stream>>>(deg, csr, cur, dinv);
            k_fillcsr<<<(B * EG + 255) / 256, 256, 0, stream>>>(eis[br], eis[br], cur, dinv, epk, B);
            int half4 = B * NN * FF / 4;
            k_convx<<<(half4 + 255) / 256, 256, 0, stream>>>(xs[br], xs[br], xbf, half4, half4);
            k_wT<<<dim3(32, 32, 1), dim3(32, 8), 0, stream>>>(Wgs[br], Wgs[br], wT);
            k_gemm<<<1024, 256, 0, stream>>>(xbf, wT, wT, hbf, 125);
            k_aggreduce<<<1000, 256, 0, stream>>>(hbf, csr, epk, dinv, bgs[br], bgs[br], part, 1000);
            k_gsum<<<B * 4, 256, 0, stream>>>(part, gsum);
            k_fc<<<B, DD, 0, stream>>>(gsum, Wfs[br], bfs[br], Wfs[br], bfs[br],
                                       g12 + (size_t)br * B * DD);
        }
        k_head<<<1, 256, 0, stream>>>(g12, W1, b1, W2, b2, Wo, bo, out);
    }
}

// Round 6
// 670.519 us; speedup vs baseline: 1.3347x; 1.0069x over previous
//
#include <hip/hip_runtime.h>
#include <stdint.h>

#define B 8
#define NN 2000
#define EG 64000
#define FF 1024
#define DD 128
#define BK 32
#define NCHUNK 125   // aggreduce chunks per graph (16 nodes each)

typedef short short8 __attribute__((ext_vector_type(8)));
typedef float f32x4 __attribute__((ext_vector_type(4)));

__device__ __forceinline__ unsigned short f2bf(float f) {
    union { float f; unsigned int u; } v; v.f = f;
    unsigned int u = v.u;
    unsigned int r = u + 0x7FFFu + ((u >> 16) & 1u);
    return (unsigned short)(r >> 16);
}
__device__ __forceinline__ float leaky(float v) { return v >= 0.0f ? v : 0.01f * v; }

// unpack uint4 = 8 bf16 and fma into r[0..7] with weight w
__device__ __forceinline__ void acc8(float* __restrict__ r, float w, uint4 v) {
    union { unsigned int u; float f; } c;
    unsigned int u;
    u = v.x; c.u = u << 16; r[0] += w * c.f; c.u = u & 0xffff0000u; r[1] += w * c.f;
    u = v.y; c.u = u << 16; r[2] += w * c.f; c.u = u & 0xffff0000u; r[3] += w * c.f;
    u = v.z; c.u = u << 16; r[4] += w * c.f; c.u = u & 0xffff0000u; r[5] += w * c.f;
    u = v.w; c.u = u << 16; r[6] += w * c.f; c.u = u & 0xffff0000u; r[7] += w * c.f;
}

// ---------------- prep kernels (batched over NG graphs) ----------------
__global__ void k_fillf(float* __restrict__ p, float v, int n) {
    int i = blockIdx.x * 256 + threadIdx.x;
    if (i < n) p[i] = v;
}

__global__ void k_degcount(const int* __restrict__ ei_a, const int* __restrict__ ei_b,
                           float* __restrict__ deg, int ng) {
    int i = blockIdx.x * 256 + threadIdx.x;
    if (i >= ng * EG) return;
    int g = i / EG, e = i - g * EG;
    const int* ei = (g < B) ? (ei_a + (size_t)g * 2 * EG) : (ei_b + (size_t)(g - B) * 2 * EG);
    int t = ei[EG + e];
    atomicAdd(&deg[g * NN + t], 1.0f);
}

// per-graph exclusive scan of in-degree -> CSR offsets, cursor init, dinv
__global__ void k_scan(const float* __restrict__ deg, int* __restrict__ csr_off,
                       int* __restrict__ cursor, float* __restrict__ dinv) {
    int g = blockIdx.x, t = threadIdx.x;
    __shared__ int part[256];
    int loc[8];
    int s = 0;
#pragma unroll
    for (int i = 0; i < 8; ++i) {
        int n = t * 8 + i;
        float dv = (n < NN) ? deg[g * NN + n] : 1.0f;
        if (n < NN) dinv[g * NN + n] = rsqrtf(dv);
        int c = (n < NN) ? ((int)dv - 1) : 0;
        loc[i] = s;
        s += c;
    }
    part[t] = s;
    __syncthreads();
    for (int off = 1; off < 256; off <<= 1) {
        int v = (t >= off) ? part[t - off] : 0;
        __syncthreads();
        part[t] += v;
        __syncthreads();
    }
    int base = part[t] - s;
#pragma unroll
    for (int i = 0; i < 8; ++i) {
        int n = t * 8 + i;
        if (n < NN) {
            int o = base + loc[i];
            csr_off[g * (NN + 1) + n] = o;
            cursor[g * NN + n] = o;
        }
    }
    if (t == 255) csr_off[g * (NN + 1) + NN] = part[255];
}

// fill CSR: packed (src, weight) per edge
__global__ void k_fillcsr(const int* __restrict__ ei_a, const int* __restrict__ ei_b,
                          int* __restrict__ cursor, const float* __restrict__ dinv,
                          int2* __restrict__ epk, int ng) {
    int i = blockIdx.x * 256 + threadIdx.x;
    if (i >= ng * EG) return;
    int g = i / EG, e = i - g * EG;
    const int* ei = (g < B) ? (ei_a + (size_t)g * 2 * EG) : (ei_b + (size_t)(g - B) * 2 * EG);
    int s = ei[e];
    int t = ei[EG + e];
    int pos = atomicAdd(&cursor[g * NN + t], 1);
    int2 p;
    p.x = s;
    p.y = __float_as_int(dinv[g * NN + s] * dinv[g * NN + t]);
    epk[(size_t)g * EG + pos] = p;
}

__global__ void k_convx(const float* __restrict__ x_a, const float* __restrict__ x_b,
                        unsigned short* __restrict__ xb, int half4, int total4) {
    int i = blockIdx.x * 256 + threadIdx.x;
    if (i >= total4) return;
    float4 v = (i < half4) ? ((const float4*)x_a)[i] : ((const float4*)x_b)[i - half4];
    ushort4 o;
    o.x = f2bf(v.x); o.y = f2bf(v.y); o.z = f2bf(v.z); o.w = f2bf(v.w);
    ((ushort4*)xb)[i] = o;
}

// transpose+convert Wg[F][F] fp32 -> wT[n][k] bf16; blockIdx.z selects weight
__global__ void k_wT(const float* __restrict__ Wg_a, const float* __restrict__ Wg_b,
                     unsigned short* __restrict__ wT) {
    __shared__ float tile[32][33];
    int tx = threadIdx.x, ty = threadIdx.y;  // 32 x 8
    int k0 = blockIdx.y * 32, n0 = blockIdx.x * 32;
    const float* Wg = blockIdx.z ? Wg_b : Wg_a;
    unsigned short* o = wT + (size_t)blockIdx.z * FF * FF;
#pragma unroll
    for (int r = 0; r < 4; ++r) {
        int row = ty + r * 8;
        tile[row][tx] = Wg[(k0 + row) * FF + n0 + tx];
    }
    __syncthreads();
#pragma unroll
    for (int r = 0; r < 4; ++r) {
        int row = ty + r * 8;
        o[(n0 + row) * FF + k0 + tx] = f2bf(tile[tx][row]);
    }
}

// ---------------- bf16 MFMA GEMM (global_load_lds staging) ----------------
// Block remap for L2 locality: blk bits [2:0]=XCD slot (part of m-tile),
// [5:3]=n-tile, [10:6]=m-group. m-tiles >= 125 use wTb.
__launch_bounds__(256) __global__
void k_gemm(const unsigned short* __restrict__ Abf, const unsigned short* __restrict__ wTa,
            const unsigned short* __restrict__ wTb, unsigned short* __restrict__ Hbf,
            int mtiles) {
    int blk = blockIdx.x;
    int mt = ((blk >> 6) << 3) | (blk & 7);
    int nt = (blk >> 3) & 7;
    if (mt >= mtiles) return;
    int m0 = mt * 128, n0 = nt * 128;
    const unsigned short* Bbf = (mt >= 125) ? wTb : wTa;

    __shared__ __align__(16) unsigned short As[128 * BK];
    __shared__ __align__(16) unsigned short Bs[128 * BK];
    int tid = threadIdx.x;
    int lane = tid & 63, wave = tid >> 6;
    int wr = wave >> 1, wc = wave & 1;
    int q = lane >> 4, l15 = lane & 15;
    int lr = lane >> 2, lc = lane & 3;

    f32x4 acc[4][4];
#pragma unroll
    for (int i = 0; i < 4; ++i)
#pragma unroll
        for (int j = 0; j < 4; ++j) acc[i][j] = (f32x4){0.f, 0.f, 0.f, 0.f};

    for (int kt = 0; kt < 32; ++kt) {
        int kb = kt * BK;
#pragma unroll
        for (int p = 0; p < 2; ++p) {
            int rbase = p * 64 + wave * 16;      // wave-uniform
            int r = rbase + lr;                  // per-lane global row
            __builtin_amdgcn_global_load_lds(
                (const __attribute__((address_space(1))) unsigned int*)
                    &Abf[(size_t)(m0 + r) * FF + kb + lc * 8],
                (__attribute__((address_space(3))) unsigned int*)&As[rbase * BK],
                16, 0, 0);
            __builtin_amdgcn_global_load_lds(
                (const __attribute__((address_space(1))) unsigned int*)
                    &Bbf[(size_t)(n0 + r) * FF + kb + lc * 8],
                (__attribute__((address_space(3))) unsigned int*)&Bs[rbase * BK],
                16, 0, 0);
        }
        __syncthreads();
        short8 fa[4], fb[4];
#pragma unroll
        for (int i = 0; i < 4; ++i)
            fa[i] = *(const short8*)&As[(wr * 64 + i * 16 + l15) * BK + q * 8];
#pragma unroll
        for (int j = 0; j < 4; ++j)
            fb[j] = *(const short8*)&Bs[(wc * 64 + j * 16 + l15) * BK + q * 8];
#pragma unroll
        for (int i = 0; i < 4; ++i)
#pragma unroll
            for (int j = 0; j < 4; ++j)
                acc[i][j] = __builtin_amdgcn_mfma_f32_16x16x32_bf16(fa[i], fb[j], acc[i][j], 0, 0, 0);
        __syncthreads();
    }
#pragma unroll
    for (int i = 0; i < 4; ++i) {
#pragma unroll
        for (int j = 0; j < 4; ++j) {
            int n = n0 + wc * 64 + j * 16 + l15;
#pragma unroll
            for (int v = 0; v < 4; ++v) {
                int m = m0 + wr * 64 + i * 16 + q * 4 + v;
                Hbf[(size_t)m * FF + n] = f2bf(acc[i][j][v]);
            }
        }
    }
}

// ---------------- fused aggregation + bias + leaky + node-sum ----------------
// Feature-half phasing: grid = nphase*1000 blocks, phase = blk/1000.
// half = phase&1, graph-set = phase>>1 (batched: sets {0-7},{8-15}).
// XCD = blk&7 -> per-XCD working set = 2.05MB H-half + 0.5MB epk < 4MB L2.
// Block: 16 nodes x 512 feats; 4 teams x 64 lanes; team does 4 nodes; lane 8 feats.
__launch_bounds__(256) __global__
void k_aggreduce(const unsigned short* __restrict__ Hbf, const int* __restrict__ csr_off,
                 const int2* __restrict__ epk, const float* __restrict__ dinv,
                 const float* __restrict__ bg_a, const float* __restrict__ bg_b,
                 float* __restrict__ part) {
    int blk = blockIdx.x;
    int phase = blk / 1000;
    int bp = blk - phase * 1000;
    int half = phase & 1;
    int g = (phase >> 1) * 8 + (bp & 7);
    int chunk = bp >> 3;         // 0..124
    int tid = threadIdx.x;
    int team = tid >> 6;         // 0..3
    int lane = tid & 63;
    int f0 = half * 512 + lane * 8;
    int n0 = chunk * 16 + team * 4;
    const unsigned short* Hb = Hbf + (size_t)g * NN * FF;
    const int2* ep = epk + (size_t)g * EG;
    const float* bg = (g < B) ? bg_a : bg_b;

    float bgv[8];
#pragma unroll
    for (int i = 0; i < 8; ++i) bgv[i] = bg[f0 + i];
    float bsum[8] = {0.f, 0.f, 0.f, 0.f, 0.f, 0.f, 0.f, 0.f};

    for (int nn = 0; nn < 4; ++nn) {
        int n = n0 + nn;
        float dn = dinv[g * NN + n];
        int beg = csr_off[g * (NN + 1) + n];
        int end = csr_off[g * (NN + 1) + n + 1];
        float racc[8] = {0.f, 0.f, 0.f, 0.f, 0.f, 0.f, 0.f, 0.f};
        {   // self-loop (weight 1/deg)
            uint4 sv = *(const uint4*)&Hb[(n << 10) + f0];
            acc8(racc, dn * dn, sv);
        }
        int j = beg;
        for (; j + 4 <= end; j += 4) {
            int2 e0 = ep[j], e1 = ep[j + 1], e2 = ep[j + 2], e3 = ep[j + 3];
            uint4 v0 = *(const uint4*)&Hb[(e0.x << 10) + f0];
            uint4 v1 = *(const uint4*)&Hb[(e1.x << 10) + f0];
            uint4 v2 = *(const uint4*)&Hb[(e2.x << 10) + f0];
            uint4 v3 = *(const uint4*)&Hb[(e3.x << 10) + f0];
            acc8(racc, __int_as_float(e0.y), v0);
            acc8(racc, __int_as_float(e1.y), v1);
            acc8(racc, __int_as_float(e2.y), v2);
            acc8(racc, __int_as_float(e3.y), v3);
        }
        for (; j < end; ++j) {
            int2 e = ep[j];
            uint4 v = *(const uint4*)&Hb[(e.x << 10) + f0];
            acc8(racc, __int_as_float(e.y), v);
        }
#pragma unroll
        for (int i = 0; i < 8; ++i) bsum[i] += leaky(racc[i] + bgv[i]);
    }

    // reduce across the 4 teams (same f-range, different nodes), then store
    __shared__ float red[3][64 * 8];
    if (team > 0) {
#pragma unroll
        for (int i = 0; i < 8; ++i) red[team - 1][lane * 8 + i] = bsum[i];
    }
    __syncthreads();
    if (team == 0) {
        float* o = part + ((size_t)g * NCHUNK + chunk) * FF + f0;
        float4 a, c;
        a.x = bsum[0] + red[0][lane * 8 + 0] + red[1][lane * 8 + 0] + red[2][lane * 8 + 0];
        a.y = bsum[1] + red[0][lane * 8 + 1] + red[1][lane * 8 + 1] + red[2][lane * 8 + 1];
        a.z = bsum[2] + red[0][lane * 8 + 2] + red[1][lane * 8 + 2] + red[2][lane * 8 + 2];
        a.w = bsum[3] + red[0][lane * 8 + 3] + red[1][lane * 8 + 3] + red[2][lane * 8 + 3];
        c.x = bsum[4] + red[0][lane * 8 + 4] + red[1][lane * 8 + 4] + red[2][lane * 8 + 4];
        c.y = bsum[5] + red[0][lane * 8 + 5] + red[1][lane * 8 + 5] + red[2][lane * 8 + 5];
        c.z = bsum[6] + red[0][lane * 8 + 6] + red[1][lane * 8 + 6] + red[2][lane * 8 + 6];
        c.w = bsum[7] + red[0][lane * 8 + 7] + red[1][lane * 8 + 7] + red[2][lane * 8 + 7];
        *(float4*)&o[0] = a;
        *(float4*)&o[4] = c;
    }
}

// fused: gsum reduction over chunks (in LDS) + fc GEMV + leaky
__global__ void k_fc(const float* __restrict__ part, const float* __restrict__ Wf_a,
                     const float* __restrict__ bf_a, const float* __restrict__ Wf_b,
                     const float* __restrict__ bf_b, float* __restrict__ g12) {
    int g = blockIdx.x, d = threadIdx.x;  // 128 threads
    __shared__ float gs[FF];
    const float* p = part + (size_t)g * NCHUNK * FF;
#pragma unroll
    for (int i = 0; i < 8; ++i) {
        int f = i * 128 + d;
        float s = 0.f;
        for (int c = 0; c < NCHUNK; ++c) s += p[(size_t)c * FF + f];
        gs[f] = s;
    }
    __syncthreads();
    const float* Wf = (g < B) ? Wf_a : Wf_b;
    const float* bfv = (g < B) ? bf_a : bf_b;
    float acc = 0.f;
#pragma unroll 8
    for (int f = 0; f < FF; ++f) acc += gs[f] * Wf[f * DD + d];
    acc = acc * (1.0f / (float)NN) + bfv[d];
    g12[g * DD + d] = leaky(acc);
}

__launch_bounds__(256) __global__
void k_head(const float* __restrict__ g, const float* __restrict__ W1, const float* __restrict__ b1,
            const float* __restrict__ W2, const float* __restrict__ b2,
            const float* __restrict__ Wo, const float* __restrict__ bo, float* __restrict__ out) {
    __shared__ float xc[8][256];
    __shared__ float l1[8][256];
    __shared__ float l2[8][64];
    int t = threadIdx.x;
#pragma unroll
    for (int i = 0; i < 8; ++i) {
        int idx = i * 256 + t;
        int b = idx >> 8, j = idx & 255;
        xc[b][j] = (j < DD) ? g[b * DD + j] : g[B * DD + b * DD + (j - DD)];
    }
    __syncthreads();
    {
        int j = t;
        float a[8];
#pragma unroll
        for (int b = 0; b < 8; ++b) a[b] = b1[j];
        for (int k = 0; k < 256; ++k) {
            float w = W1[k * 256 + j];
#pragma unroll
            for (int b = 0; b < 8; ++b) a[b] += xc[b][k] * w;
        }
#pragma unroll
        for (int b = 0; b < 8; ++b) l1[b][j] = leaky(a[b]);
    }
    __syncthreads();
    if (t < 64) {
        int j = t;
        float a[8];
#pragma unroll
        for (int b = 0; b < 8; ++b) a[b] = b2[j];
        for (int k = 0; k < 256; ++k) {
            float w = W2[k * 64 + j];
#pragma unroll
            for (int b = 0; b < 8; ++b) a[b] += l1[b][k] * w;
        }
#pragma unroll
        for (int b = 0; b < 8; ++b) l2[b][j] = leaky(a[b]);
    }
    __syncthreads();
    if (t < 8) {
        float a = bo[0];
        for (int k = 0; k < 64; ++k) a += l2[t][k] * Wo[k];
        out[t] = 1.0f / (1.0f + expf(-a));
    }
}

extern "C" void kernel_launch(void* const* d_in, const int* in_sizes, int n_in,
                              void* d_out, int out_size, void* d_ws, size_t ws_size,
                              hipStream_t stream) {
    const float* x1  = (const float*)d_in[0];
    const int*   ei1 = (const int*)d_in[1];
    const float* x2  = (const float*)d_in[2];
    const int*   ei2 = (const int*)d_in[3];
    const float* Wg1 = (const float*)d_in[4];
    const float* bg1 = (const float*)d_in[5];
    const float* Wf1 = (const float*)d_in[6];
    const float* bf1 = (const float*)d_in[7];
    const float* Wg2 = (const float*)d_in[8];
    const float* bg2 = (const float*)d_in[9];
    const float* Wf2 = (const float*)d_in[10];
    const float* bf2 = (const float*)d_in[11];
    const float* W1  = (const float*)d_in[12];
    const float* b1  = (const float*)d_in[13];
    const float* W2  = (const float*)d_in[14];
    const float* b2  = (const float*)d_in[15];
    const float* Wo  = (const float*)d_in[16];
    const float* bo  = (const float*)d_in[17];
    float* out = (float*)d_out;

    // ---- batched (NG=16) workspace layout ----
    auto align = [](size_t v) { return (v + 255) & ~(size_t)255; };
    size_t need = 0;
    size_t o_deg  = need; need += align((size_t)16 * NN * 4);
    size_t o_dinv = need; need += align((size_t)16 * NN * 4);
    size_t o_csr  = need; need += align((size_t)16 * (NN + 1) * 4);
    size_t o_cur  = need; need += align((size_t)16 * NN * 4);
    size_t o_epk  = need; need += align((size_t)16 * EG * 8);
    size_t o_xbf  = need; need += align((size_t)16 * NN * FF * 2);
    size_t o_wT   = need; need += align((size_t)2 * FF * FF * 2);
    size_t o_hbf  = need; need += align((size_t)16 * NN * FF * 2);
    size_t o_part = need; need += align((size_t)16 * NCHUNK * FF * 4);
    size_t o_g12  = need; need += align((size_t)16 * DD * 4);

    char* w = (char*)d_ws;
    if (ws_size >= need) {
        // ---------- fully batched path: 10 dispatches ----------
        float* deg   = (float*)(w + o_deg);
        float* dinv  = (float*)(w + o_dinv);
        int* csr     = (int*)(w + o_csr);
        int* cur     = (int*)(w + o_cur);
        int2* epk    = (int2*)(w + o_epk);
        unsigned short* xbf = (unsigned short*)(w + o_xbf);
        unsigned short* wT  = (unsigned short*)(w + o_wT);
        unsigned short* hbf = (unsigned short*)(w + o_hbf);
        float* part  = (float*)(w + o_part);
        float* g12   = (float*)(w + o_g12);

        k_fillf<<<(16 * NN + 255) / 256, 256, 0, stream>>>(deg, 1.0f, 16 * NN);
        k_degcount<<<(16 * EG + 255) / 256, 256, 0, stream>>>(ei1, ei2, deg, 16);
        k_scan<<<16, 256, 0, stream>>>(deg, csr, cur, dinv);
        k_fillcsr<<<(16 * EG + 255) / 256, 256, 0, stream>>>(ei1, ei2, cur, dinv, epk, 16);
        int half4 = B * NN * FF / 4;
        k_convx<<<(2 * half4 + 255) / 256, 256, 0, stream>>>(x1, x2, xbf, half4, 2 * half4);
        k_wT<<<dim3(32, 32, 2), dim3(32, 8), 0, stream>>>(Wg1, Wg2, wT);
        k_gemm<<<2048, 256, 0, stream>>>(xbf, wT, wT + (size_t)FF * FF, hbf, 250);
        k_aggreduce<<<4000, 256, 0, stream>>>(hbf, csr, epk, dinv, bg1, bg2, part);
        k_fc<<<16, DD, 0, stream>>>(part, Wf1, bf1, Wf2, bf2, g12);
        k_head<<<1, 256, 0, stream>>>(g12, W1, b1, W2, b2, Wo, bo, out);
    } else {
        // ---------- sequential fallback (NG=8 per branch) ----------
        size_t n2 = 0;
        size_t f_deg  = n2; n2 += align((size_t)B * NN * 4);
        size_t f_dinv = n2; n2 += align((size_t)B * NN * 4);
        size_t f_csr  = n2; n2 += align((size_t)B * (NN + 1) * 4);
        size_t f_cur  = n2; n2 += align((size_t)B * NN * 4);
        size_t f_epk  = n2; n2 += align((size_t)B * EG * 8);
        size_t f_xbf  = n2; n2 += align((size_t)B * NN * FF * 2);
        size_t f_wT   = n2; n2 += align((size_t)FF * FF * 2);
        size_t f_hbf  = n2; n2 += align((size_t)B * NN * FF * 2);
        size_t f_part = n2; n2 += align((size_t)B * NCHUNK * FF * 4);
        size_t f_g12  = n2; n2 += align((size_t)2 * B * DD * 4);

        float* deg   = (float*)(w + f_deg);
        float* dinv  = (float*)(w + f_dinv);
        int* csr     = (int*)(w + f_csr);
        int* cur     = (int*)(w + f_cur);
        int2* epk    = (int2*)(w + f_epk);
        unsigned short* xbf = (unsigned short*)(w + f_xbf);
        unsigned short* wT  = (unsigned short*)(w + f_wT);
        unsigned short* hbf = (unsigned short*)(w + f_hbf);
        float* part  = (float*)(w + f_part);
        float* g12   = (float*)(w + f_g12);

        const float* xs[2]  = {x1, x2};
        const int*   eis[2] = {ei1, ei2};
        const float* Wgs[2] = {Wg1, Wg2};
        const float* bgs[2] = {bg1, bg2};
        const float* Wfs[2] = {Wf1, Wf2};
        const float* bfs[2] = {bf1, bf2};

        for (int br = 0; br < 2; ++br) {
            k_fillf<<<(B * NN + 255) / 256, 256, 0, stream>>>(deg, 1.0f, B * NN);
            k_degcount<<<(B * EG + 255) / 256, 256, 0, stream>>>(eis[br], eis[br], deg, B);
            k_scan<<<B, 256, 0, stream>>>(deg, csr, cur, dinv);
            k_fillcsr<<<(B * EG + 255) / 256, 256, 0, stream>>>(eis[br], eis[br], cur, dinv, epk, B);
            int half4 = B * NN * FF / 4;
            k_convx<<<(half4 + 255) / 256, 256, 0, stream>>>(xs[br], xs[br], xbf, half4, half4);
            k_wT<<<dim3(32, 32, 1), dim3(32, 8), 0, stream>>>(Wgs[br], Wgs[br], wT);
            k_gemm<<<1024, 256, 0, stream>>>(xbf, wT, wT, hbf, 125);
            k_aggreduce<<<2000, 256, 0, stream>>>(hbf, csr, epk, dinv, bgs[br], bgs[br], part);
            k_fc<<<B, DD, 0, stream>>>(part, Wfs[br], bfs[br], Wfs[br], bfs[br],
                                       g12 + (size_t)br * B * DD);
        }
        k_head<<<1, 256, 0, stream>>>(g12, W1, b1, W2, b2, Wo, bo, out);
    }
}

// Round 7
// 621.239 us; speedup vs baseline: 1.4406x; 1.0793x over previous
//
#include <hip/hip_runtime.h>
#include <stdint.h>

#define B 8
#define NN 2000
#define EG 64000
#define FF 1024
#define DD 128
#define BK 32
#define NCHUNK 125   // aggreduce chunks per graph (16 nodes each)
#define CG 5         // chunk groups for gsum tree (25 chunks each)

typedef short short8 __attribute__((ext_vector_type(8)));
typedef float f32x4 __attribute__((ext_vector_type(4)));
typedef float f32x2 __attribute__((ext_vector_type(2)));

__device__ __forceinline__ unsigned short f2bf(float f) {
    union { float f; unsigned int u; } v; v.f = f;
    unsigned int u = v.u;
    unsigned int r = u + 0x7FFFu + ((u >> 16) & 1u);
    return (unsigned short)(r >> 16);
}
__device__ __forceinline__ float leaky(float v) { return v >= 0.0f ? v : 0.01f * v; }

// unpack uint4 = 8 bf16, packed fma into r2[0..3] (f32x2 lanes -> v_pk_fma_f32)
__device__ __forceinline__ void acc8p(f32x2* __restrict__ r, float w, uint4 v) {
    union { unsigned int u; float f; } c;
    f32x2 wv = {w, w};
    f32x2 h;
    c.u = v.x << 16;          h.x = c.f;
    c.u = v.x & 0xffff0000u;  h.y = c.f;
    r[0] += wv * h;
    c.u = v.y << 16;          h.x = c.f;
    c.u = v.y & 0xffff0000u;  h.y = c.f;
    r[1] += wv * h;
    c.u = v.z << 16;          h.x = c.f;
    c.u = v.z & 0xffff0000u;  h.y = c.f;
    r[2] += wv * h;
    c.u = v.w << 16;          h.x = c.f;
    c.u = v.w & 0xffff0000u;  h.y = c.f;
    r[3] += wv * h;
}

// ---------------- prep kernels (batched over NG graphs) ----------------
__global__ void k_fillf(float* __restrict__ p, float v, int n) {
    int i = blockIdx.x * 256 + threadIdx.x;
    if (i < n) p[i] = v;
}

__global__ void k_degcount(const int* __restrict__ ei_a, const int* __restrict__ ei_b,
                           float* __restrict__ deg, int ng) {
    int i = blockIdx.x * 256 + threadIdx.x;
    if (i >= ng * EG) return;
    int g = i / EG, e = i - g * EG;
    const int* ei = (g < B) ? (ei_a + (size_t)g * 2 * EG) : (ei_b + (size_t)(g - B) * 2 * EG);
    int t = ei[EG + e];
    atomicAdd(&deg[g * NN + t], 1.0f);
}

// per-graph exclusive scan of in-degree -> CSR offsets, cursor init, dinv
__global__ void k_scan(const float* __restrict__ deg, int* __restrict__ csr_off,
                       int* __restrict__ cursor, float* __restrict__ dinv) {
    int g = blockIdx.x, t = threadIdx.x;
    __shared__ int part[256];
    int loc[8];
    int s = 0;
#pragma unroll
    for (int i = 0; i < 8; ++i) {
        int n = t * 8 + i;
        float dv = (n < NN) ? deg[g * NN + n] : 1.0f;
        if (n < NN) dinv[g * NN + n] = rsqrtf(dv);
        int c = (n < NN) ? ((int)dv - 1) : 0;
        loc[i] = s;
        s += c;
    }
    part[t] = s;
    __syncthreads();
    for (int off = 1; off < 256; off <<= 1) {
        int v = (t >= off) ? part[t - off] : 0;
        __syncthreads();
        part[t] += v;
        __syncthreads();
    }
    int base = part[t] - s;
#pragma unroll
    for (int i = 0; i < 8; ++i) {
        int n = t * 8 + i;
        if (n < NN) {
            int o = base + loc[i];
            csr_off[g * (NN + 1) + n] = o;
            cursor[g * NN + n] = o;
        }
    }
    if (t == 255) csr_off[g * (NN + 1) + NN] = part[255];
}

// fill CSR: packed (src, weight) per edge
__global__ void k_fillcsr(const int* __restrict__ ei_a, const int* __restrict__ ei_b,
                          int* __restrict__ cursor, const float* __restrict__ dinv,
                          int2* __restrict__ epk, int ng) {
    int i = blockIdx.x * 256 + threadIdx.x;
    if (i >= ng * EG) return;
    int g = i / EG, e = i - g * EG;
    const int* ei = (g < B) ? (ei_a + (size_t)g * 2 * EG) : (ei_b + (size_t)(g - B) * 2 * EG);
    int s = ei[e];
    int t = ei[EG + e];
    int pos = atomicAdd(&cursor[g * NN + t], 1);
    int2 p;
    p.x = s;
    p.y = __float_as_int(dinv[g * NN + s] * dinv[g * NN + t]);
    epk[(size_t)g * EG + pos] = p;
}

__global__ void k_convx(const float* __restrict__ x_a, const float* __restrict__ x_b,
                        unsigned short* __restrict__ xb, int half4, int total4) {
    int i = blockIdx.x * 256 + threadIdx.x;
    if (i >= total4) return;
    float4 v = (i < half4) ? ((const float4*)x_a)[i] : ((const float4*)x_b)[i - half4];
    ushort4 o;
    o.x = f2bf(v.x); o.y = f2bf(v.y); o.z = f2bf(v.z); o.w = f2bf(v.w);
    ((ushort4*)xb)[i] = o;
}

// transpose+convert Wg[F][F] fp32 -> wT[n][k] bf16; blockIdx.z selects weight
__global__ void k_wT(const float* __restrict__ Wg_a, const float* __restrict__ Wg_b,
                     unsigned short* __restrict__ wT) {
    __shared__ float tile[32][33];
    int tx = threadIdx.x, ty = threadIdx.y;  // 32 x 8
    int k0 = blockIdx.y * 32, n0 = blockIdx.x * 32;
    const float* Wg = blockIdx.z ? Wg_b : Wg_a;
    unsigned short* o = wT + (size_t)blockIdx.z * FF * FF;
#pragma unroll
    for (int r = 0; r < 4; ++r) {
        int row = ty + r * 8;
        tile[row][tx] = Wg[(k0 + row) * FF + n0 + tx];
    }
    __syncthreads();
#pragma unroll
    for (int r = 0; r < 4; ++r) {
        int row = ty + r * 8;
        o[(n0 + row) * FF + k0 + tx] = f2bf(tile[tx][row]);
    }
}

// ---------------- bf16 MFMA GEMM (global_load_lds staging) ----------------
// Block remap for L2 locality: blk bits [2:0]=XCD slot (part of m-tile),
// [5:3]=n-tile, [10:6]=m-group. m-tiles >= 125 use wTb.
__launch_bounds__(256) __global__
void k_gemm(const unsigned short* __restrict__ Abf, const unsigned short* __restrict__ wTa,
            const unsigned short* __restrict__ wTb, unsigned short* __restrict__ Hbf,
            int mtiles) {
    int blk = blockIdx.x;
    int mt = ((blk >> 6) << 3) | (blk & 7);
    int nt = (blk >> 3) & 7;
    if (mt >= mtiles) return;
    int m0 = mt * 128, n0 = nt * 128;
    const unsigned short* Bbf = (mt >= 125) ? wTb : wTa;

    __shared__ __align__(16) unsigned short As[128 * BK];
    __shared__ __align__(16) unsigned short Bs[128 * BK];
    int tid = threadIdx.x;
    int lane = tid & 63, wave = tid >> 6;
    int wr = wave >> 1, wc = wave & 1;
    int q = lane >> 4, l15 = lane & 15;
    int lr = lane >> 2, lc = lane & 3;

    f32x4 acc[4][4];
#pragma unroll
    for (int i = 0; i < 4; ++i)
#pragma unroll
        for (int j = 0; j < 4; ++j) acc[i][j] = (f32x4){0.f, 0.f, 0.f, 0.f};

    for (int kt = 0; kt < 32; ++kt) {
        int kb = kt * BK;
#pragma unroll
        for (int p = 0; p < 2; ++p) {
            int rbase = p * 64 + wave * 16;      // wave-uniform
            int r = rbase + lr;                  // per-lane global row
            __builtin_amdgcn_global_load_lds(
                (const __attribute__((address_space(1))) unsigned int*)
                    &Abf[(size_t)(m0 + r) * FF + kb + lc * 8],
                (__attribute__((address_space(3))) unsigned int*)&As[rbase * BK],
                16, 0, 0);
            __builtin_amdgcn_global_load_lds(
                (const __attribute__((address_space(1))) unsigned int*)
                    &Bbf[(size_t)(n0 + r) * FF + kb + lc * 8],
                (__attribute__((address_space(3))) unsigned int*)&Bs[rbase * BK],
                16, 0, 0);
        }
        __syncthreads();
        short8 fa[4], fb[4];
#pragma unroll
        for (int i = 0; i < 4; ++i)
            fa[i] = *(const short8*)&As[(wr * 64 + i * 16 + l15) * BK + q * 8];
#pragma unroll
        for (int j = 0; j < 4; ++j)
            fb[j] = *(const short8*)&Bs[(wc * 64 + j * 16 + l15) * BK + q * 8];
#pragma unroll
        for (int i = 0; i < 4; ++i)
#pragma unroll
            for (int j = 0; j < 4; ++j)
                acc[i][j] = __builtin_amdgcn_mfma_f32_16x16x32_bf16(fa[i], fb[j], acc[i][j], 0, 0, 0);
        __syncthreads();
    }
#pragma unroll
    for (int i = 0; i < 4; ++i) {
#pragma unroll
        for (int j = 0; j < 4; ++j) {
            int n = n0 + wc * 64 + j * 16 + l15;
#pragma unroll
            for (int v = 0; v < 4; ++v) {
                int m = m0 + wr * 64 + i * 16 + q * 4 + v;
                Hbf[(size_t)m * FF + n] = f2bf(acc[i][j][v]);
            }
        }
    }
}

// ---------------- fused aggregation + bias + leaky + node-sum ----------------
// Feature-half phasing: grid = nphase*1000 blocks, phase = blk/1000.
// half = phase&1, graph-set = phase>>1. XCD = blk&7 -> per-XCD working set =
// 2.05MB H-half + 0.5MB epk < 4MB L2. Inner math in f32x2 (v_pk_fma_f32).
__launch_bounds__(256) __global__
void k_aggreduce(const unsigned short* __restrict__ Hbf, const int* __restrict__ csr_off,
                 const int2* __restrict__ epk, const float* __restrict__ dinv,
                 const float* __restrict__ bg_a, const float* __restrict__ bg_b,
                 float* __restrict__ part) {
    int blk = blockIdx.x;
    int phase = blk / 1000;
    int bp = blk - phase * 1000;
    int half = phase & 1;
    int g = (phase >> 1) * 8 + (bp & 7);
    int chunk = bp >> 3;         // 0..124
    int tid = threadIdx.x;
    int team = tid >> 6;         // 0..3
    int lane = tid & 63;
    int f0 = half * 512 + lane * 8;
    int n0 = chunk * 16 + team * 4;
    const unsigned short* Hb = Hbf + (size_t)g * NN * FF;
    const int2* ep = epk + (size_t)g * EG;
    const float* bg = (g < B) ? bg_a : bg_b;

    f32x2 bgv[4];
#pragma unroll
    for (int i = 0; i < 4; ++i) bgv[i] = (f32x2){bg[f0 + 2 * i], bg[f0 + 2 * i + 1]};
    f32x2 bsum[4];
#pragma unroll
    for (int i = 0; i < 4; ++i) bsum[i] = (f32x2){0.f, 0.f};

    for (int nn = 0; nn < 4; ++nn) {
        int n = n0 + nn;
        float dn = dinv[g * NN + n];
        int beg = csr_off[g * (NN + 1) + n];
        int end = csr_off[g * (NN + 1) + n + 1];
        f32x2 racc[4];
#pragma unroll
        for (int i = 0; i < 4; ++i) racc[i] = (f32x2){0.f, 0.f};
        {   // self-loop (weight 1/deg)
            uint4 sv = *(const uint4*)&Hb[(n << 10) + f0];
            acc8p(racc, dn * dn, sv);
        }
        int j = beg;
        for (; j + 4 <= end; j += 4) {
            int2 e0 = ep[j], e1 = ep[j + 1], e2 = ep[j + 2], e3 = ep[j + 3];
            uint4 v0 = *(const uint4*)&Hb[(e0.x << 10) + f0];
            uint4 v1 = *(const uint4*)&Hb[(e1.x << 10) + f0];
            uint4 v2 = *(const uint4*)&Hb[(e2.x << 10) + f0];
            uint4 v3 = *(const uint4*)&Hb[(e3.x << 10) + f0];
            acc8p(racc, __int_as_float(e0.y), v0);
            acc8p(racc, __int_as_float(e1.y), v1);
            acc8p(racc, __int_as_float(e2.y), v2);
            acc8p(racc, __int_as_float(e3.y), v3);
        }
        for (; j < end; ++j) {
            int2 e = ep[j];
            uint4 v = *(const uint4*)&Hb[(e.x << 10) + f0];
            acc8p(racc, __int_as_float(e.y), v);
        }
#pragma unroll
        for (int i = 0; i < 4; ++i) {
            f32x2 t = racc[i] + bgv[i];
            bsum[i].x += leaky(t.x);
            bsum[i].y += leaky(t.y);
        }
    }

    // reduce across the 4 teams; stride-9 padding avoids bank conflicts
    __shared__ float red[3][64 * 9];
    if (team > 0) {
#pragma unroll
        for (int i = 0; i < 4; ++i) {
            red[team - 1][lane * 9 + 2 * i]     = bsum[i].x;
            red[team - 1][lane * 9 + 2 * i + 1] = bsum[i].y;
        }
    }
    __syncthreads();
    if (team == 0) {
        float* o = part + ((size_t)g * NCHUNK + chunk) * FF + f0;
        float r[8];
#pragma unroll
        for (int i = 0; i < 4; ++i) {
            r[2 * i]     = bsum[i].x;
            r[2 * i + 1] = bsum[i].y;
        }
#pragma unroll
        for (int t = 0; t < 3; ++t)
#pragma unroll
            for (int i = 0; i < 8; ++i) r[i] += red[t][lane * 9 + i];
        float4 a = {r[0], r[1], r[2], r[3]};
        float4 c = {r[4], r[5], r[6], r[7]};
        *(float4*)&o[0] = a;
        *(float4*)&o[4] = c;
    }
}

// tree level 1: sum 25 chunks -> part2[g][cg][f]
__global__ void k_gsum1(const float* __restrict__ part, float* __restrict__ part2) {
    int blk = blockIdx.x;               // g*20 + fq*5 + cg
    int g = blk / 20;
    int rem = blk - g * 20;
    int fq = rem / CG, cg = rem - fq * CG;
    int f = fq * 256 + threadIdx.x;
    const float* p = part + (size_t)g * NCHUNK * FF + (size_t)cg * 25 * FF + f;
    float s = 0.f;
#pragma unroll 5
    for (int c = 0; c < 25; ++c) s += p[(size_t)c * FF];
    part2[((size_t)g * CG + cg) * FF + f] = s;
}

// fc: sum 5 partials in LDS + GEMV + leaky
__global__ void k_fc(const float* __restrict__ part2, const float* __restrict__ Wf_a,
                     const float* __restrict__ bf_a, const float* __restrict__ Wf_b,
                     const float* __restrict__ bf_b, float* __restrict__ g12) {
    int g = blockIdx.x, d = threadIdx.x;  // 128 threads
    __shared__ float gs[FF];
    const float* p = part2 + (size_t)g * CG * FF;
#pragma unroll
    for (int i = 0; i < 8; ++i) {
        int f = i * 128 + d;
        float s = 0.f;
#pragma unroll
        for (int c = 0; c < CG; ++c) s += p[(size_t)c * FF + f];
        gs[f] = s;
    }
    __syncthreads();
    const float* Wf = (g < B) ? Wf_a : Wf_b;
    const float* bfv = (g < B) ? bf_a : bf_b;
    float acc = 0.f;
#pragma unroll 8
    for (int f = 0; f < FF; ++f) acc += gs[f] * Wf[f * DD + d];
    acc = acc * (1.0f / (float)NN) + bfv[d];
    g12[g * DD + d] = leaky(acc);
}

__launch_bounds__(256) __global__
void k_head(const float* __restrict__ g, const float* __restrict__ W1, const float* __restrict__ b1,
            const float* __restrict__ W2, const float* __restrict__ b2,
            const float* __restrict__ Wo, const float* __restrict__ bo, float* __restrict__ out) {
    __shared__ float xc[8][256];
    __shared__ float l1[8][256];
    __shared__ float l2[8][64];
    int t = threadIdx.x;
#pragma unroll
    for (int i = 0; i < 8; ++i) {
        int idx = i * 256 + t;
        int b = idx >> 8, j = idx & 255;
        xc[b][j] = (j < DD) ? g[b * DD + j] : g[B * DD + b * DD + (j - DD)];
    }
    __syncthreads();
    {
        int j = t;
        float a[8];
#pragma unroll
        for (int b = 0; b < 8; ++b) a[b] = b1[j];
        for (int k = 0; k < 256; ++k) {
            float w = W1[k * 256 + j];
#pragma unroll
            for (int b = 0; b < 8; ++b) a[b] += xc[b][k] * w;
        }
#pragma unroll
        for (int b = 0; b < 8; ++b) l1[b][j] = leaky(a[b]);
    }
    __syncthreads();
    if (t < 64) {
        int j = t;
        float a[8];
#pragma unroll
        for (int b = 0; b < 8; ++b) a[b] = b2[j];
        for (int k = 0; k < 256; ++k) {
            float w = W2[k * 64 + j];
#pragma unroll
            for (int b = 0; b < 8; ++b) a[b] += l1[b][k] * w;
        }
#pragma unroll
        for (int b = 0; b < 8; ++b) l2[b][j] = leaky(a[b]);
    }
    __syncthreads();
    if (t < 8) {
        float a = bo[0];
        for (int k = 0; k < 64; ++k) a += l2[t][k] * Wo[k];
        out[t] = 1.0f / (1.0f + expf(-a));
    }
}

extern "C" void kernel_launch(void* const* d_in, const int* in_sizes, int n_in,
                              void* d_out, int out_size, void* d_ws, size_t ws_size,
                              hipStream_t stream) {
    const float* x1  = (const float*)d_in[0];
    const int*   ei1 = (const int*)d_in[1];
    const float* x2  = (const float*)d_in[2];
    const int*   ei2 = (const int*)d_in[3];
    const float* Wg1 = (const float*)d_in[4];
    const float* bg1 = (const float*)d_in[5];
    const float* Wf1 = (const float*)d_in[6];
    const float* bf1 = (const float*)d_in[7];
    const float* Wg2 = (const float*)d_in[8];
    const float* bg2 = (const float*)d_in[9];
    const float* Wf2 = (const float*)d_in[10];
    const float* bf2 = (const float*)d_in[11];
    const float* W1  = (const float*)d_in[12];
    const float* b1  = (const float*)d_in[13];
    const float* W2  = (const float*)d_in[14];
    const float* b2  = (const float*)d_in[15];
    const float* Wo  = (const float*)d_in[16];
    const float* bo  = (const float*)d_in[17];
    float* out = (float*)d_out;

    // ---- batched (NG=16) workspace layout ----
    auto align = [](size_t v) { return (v + 255) & ~(size_t)255; };
    size_t need = 0;
    size_t o_deg  = need; need += align((size_t)16 * NN * 4);
    size_t o_dinv = need; need += align((size_t)16 * NN * 4);
    size_t o_csr  = need; need += align((size_t)16 * (NN + 1) * 4);
    size_t o_cur  = need; need += align((size_t)16 * NN * 4);
    size_t o_epk  = need; need += align((size_t)16 * EG * 8);
    size_t o_xbf  = need; need += align((size_t)16 * NN * FF * 2);
    size_t o_wT   = need; need += align((size_t)2 * FF * FF * 2);
    size_t o_hbf  = need; need += align((size_t)16 * NN * FF * 2);
    size_t o_part = need; need += align((size_t)16 * NCHUNK * FF * 4);
    size_t o_pt2  = need; need += align((size_t)16 * CG * FF * 4);
    size_t o_g12  = need; need += align((size_t)16 * DD * 4);

    char* w = (char*)d_ws;
    if (ws_size >= need) {
        // ---------- fully batched path: 11 dispatches ----------
        float* deg   = (float*)(w + o_deg);
        float* dinv  = (float*)(w + o_dinv);
        int* csr     = (int*)(w + o_csr);
        int* cur     = (int*)(w + o_cur);
        int2* epk    = (int2*)(w + o_epk);
        unsigned short* xbf = (unsigned short*)(w + o_xbf);
        unsigned short* wT  = (unsigned short*)(w + o_wT);
        unsigned short* hbf = (unsigned short*)(w + o_hbf);
        float* part  = (float*)(w + o_part);
        float* part2 = (float*)(w + o_pt2);
        float* g12   = (float*)(w + o_g12);

        k_fillf<<<(16 * NN + 255) / 256, 256, 0, stream>>>(deg, 1.0f, 16 * NN);
        k_degcount<<<(16 * EG + 255) / 256, 256, 0, stream>>>(ei1, ei2, deg, 16);
        k_scan<<<16, 256, 0, stream>>>(deg, csr, cur, dinv);
        k_fillcsr<<<(16 * EG + 255) / 256, 256, 0, stream>>>(ei1, ei2, cur, dinv, epk, 16);
        int half4 = B * NN * FF / 4;
        k_convx<<<(2 * half4 + 255) / 256, 256, 0, stream>>>(x1, x2, xbf, half4, 2 * half4);
        k_wT<<<dim3(32, 32, 2), dim3(32, 8), 0, stream>>>(Wg1, Wg2, wT);
        k_gemm<<<2048, 256, 0, stream>>>(xbf, wT, wT + (size_t)FF * FF, hbf, 250);
        k_aggreduce<<<4000, 256, 0, stream>>>(hbf, csr, epk, dinv, bg1, bg2, part);
        k_gsum1<<<16 * 20, 256, 0, stream>>>(part, part2);
        k_fc<<<16, DD, 0, stream>>>(part2, Wf1, bf1, Wf2, bf2, g12);
        k_head<<<1, 256, 0, stream>>>(g12, W1, b1, W2, b2, Wo, bo, out);
    } else {
        // ---------- sequential fallback (NG=8 per branch) ----------
        size_t n2 = 0;
        size_t f_deg  = n2; n2 += align((size_t)B * NN * 4);
        size_t f_dinv = n2; n2 += align((size_t)B * NN * 4);
        size_t f_csr  = n2; n2 += align((size_t)B * (NN + 1) * 4);
        size_t f_cur  = n2; n2 += align((size_t)B * NN * 4);
        size_t f_epk  = n2; n2 += align((size_t)B * EG * 8);
        size_t f_xbf  = n2; n2 += align((size_t)B * NN * FF * 2);
        size_t f_wT   = n2; n2 += align((size_t)FF * FF * 2);
        size_t f_hbf  = n2; n2 += align((size_t)B * NN * FF * 2);
        size_t f_part = n2; n2 += align((size_t)B * NCHUNK * FF * 4);
        size_t f_pt2  = n2; n2 += align((size_t)B * CG * FF * 4);
        size_t f_g12  = n2; n2 += align((size_t)2 * B * DD * 4);

        float* deg   = (float*)(w + f_deg);
        float* dinv  = (float*)(w + f_dinv);
        int* csr     = (int*)(w + f_csr);
        int* cur     = (int*)(w + f_cur);
        int2* epk    = (int2*)(w + f_epk);
        unsigned short* xbf = (unsigned short*)(w + f_xbf);
        unsigned short* wT  = (unsigned short*)(w + f_wT);
        unsigned short* hbf = (unsigned short*)(w + f_hbf);
        float* part  = (float*)(w + f_part);
        float* part2 = (float*)(w + f_pt2);
        float* g12   = (float*)(w + f_g12);

        const float* xs[2]  = {x1, x2};
        const int*   eis[2] = {ei1, ei2};
        const float* Wgs[2] = {Wg1, Wg2};
        const float* bgs[2] = {bg1, bg2};
        const float* Wfs[2] = {Wf1, Wf2};
        const float* bfs[2] = {bf1, bf2};

        for (int br = 0; br < 2; ++br) {
            k_fillf<<<(B * NN + 255) / 256, 256, 0, stream>>>(deg, 1.0f, B * NN);
            k_degcount<<<(B * EG + 255) / 256, 256, 0, stream>>>(eis[br], eis[br], deg, B);
            k_scan<<<B, 256, 0, stream>>>(deg, csr, cur, dinv);
            k_fillcsr<<<(B * EG + 255) / 256, 256, 0, stream>>>(eis[br], eis[br], cur, dinv, epk, B);
            int half4 = B * NN * FF / 4;
            k_convx<<<(half4 + 255) / 256, 256, 0, stream>>>(xs[br], xs[br], xbf, half4, half4);
            k_wT<<<dim3(32, 32, 1), dim3(32, 8), 0, stream>>>(Wgs[br], Wgs[br], wT);
            k_gemm<<<1024, 256, 0, stream>>>(xbf, wT, wT, hbf, 125);
            k_aggreduce<<<2000, 256, 0, stream>>>(hbf, csr, epk, dinv, bgs[br], bgs[br], part);
            k_gsum1<<<B * 20, 256, 0, stream>>>(part, part2);
            k_fc<<<B, DD, 0, stream>>>(part2, Wfs[br], bfs[br], Wfs[br], bfs[br],
                                       g12 + (size_t)br * B * DD);
        }
        k_head<<<1, 256, 0, stream>>>(g12, W1, b1, W2, b2, Wo, bo, out);
    }
}

// Round 8
// 573.307 us; speedup vs baseline: 1.5610x; 1.0836x over previous
//
#include <hip/hip_runtime.h>
#include <stdint.h>

#define B 8
#define NN 2000
#define EG 64000
#define FF 1024
#define DD 128
#define BK 32
#define NCHUNK 125   // aggreduce chunks per graph (16 nodes each)
#define CG 5         // chunk groups for gsum tree (25 chunks each)

// k_prep block ranges
#define NB_CONV 32000   // 16*2000*1024/4 float4 / 256
#define NB_WT   2048    // 32*32*2 tiles
#define NB_DEG  4000    // 16*64000 / 256
// k_gemm_fill block ranges
#define NB_GEMM 2048
#define NB_FILL 4000

typedef short short8 __attribute__((ext_vector_type(8)));
typedef float f32x4 __attribute__((ext_vector_type(4)));
typedef float f32x2 __attribute__((ext_vector_type(2)));

__device__ __forceinline__ unsigned short f2bf(float f) {
    union { float f; unsigned int u; } v; v.f = f;
    unsigned int u = v.u;
    unsigned int r = u + 0x7FFFu + ((u >> 16) & 1u);
    return (unsigned short)(r >> 16);
}
__device__ __forceinline__ float leaky(float v) { return v >= 0.0f ? v : 0.01f * v; }

// unpack uint4 = 8 bf16, packed fma into r[0..3] (f32x2 lanes -> v_pk_fma_f32)
__device__ __forceinline__ void acc8p(f32x2* __restrict__ r, float w, uint4 v) {
    union { unsigned int u; float f; } c;
    f32x2 wv = {w, w};
    f32x2 h;
    c.u = v.x << 16;          h.x = c.f;
    c.u = v.x & 0xffff0000u;  h.y = c.f;
    r[0] += wv * h;
    c.u = v.y << 16;          h.x = c.f;
    c.u = v.y & 0xffff0000u;  h.y = c.f;
    r[1] += wv * h;
    c.u = v.z << 16;          h.x = c.f;
    c.u = v.z & 0xffff0000u;  h.y = c.f;
    r[2] += wv * h;
    c.u = v.w << 16;          h.x = c.f;
    c.u = v.w & 0xffff0000u;  h.y = c.f;
    r[3] += wv * h;
}

// ---------------- fused prep: convx + wT transpose + degcount ----------------
// deg (int) must be zeroed beforehand (hipMemsetAsync node).
__global__ void k_prep(const float* __restrict__ x_a, const float* __restrict__ x_b,
                       unsigned short* __restrict__ xb,
                       const float* __restrict__ Wg_a, const float* __restrict__ Wg_b,
                       unsigned short* __restrict__ wT,
                       const int* __restrict__ ei_a, const int* __restrict__ ei_b,
                       int* __restrict__ degi) {
    int blk = blockIdx.x;
    int tid = threadIdx.x;
    __shared__ float tile[32][33];
    if (blk < NB_CONV) {
        // convert x1,x2 fp32 -> bf16 (exact multiple: no bound check)
        int i = blk * 256 + tid;
        float4 v = (i < NB_CONV * 128) ? ((const float4*)x_a)[i]
                                       : ((const float4*)x_b)[i - NB_CONV * 128];
        ushort4 o;
        o.x = f2bf(v.x); o.y = f2bf(v.y); o.z = f2bf(v.z); o.w = f2bf(v.w);
        ((ushort4*)xb)[i] = o;
    } else if (blk < NB_CONV + NB_WT) {
        // transpose+convert Wg -> wT[n][k] bf16
        int b2 = blk - NB_CONV;
        int z = b2 >> 10, rem = b2 & 1023;
        int by = rem >> 5, bx = rem & 31;
        int tx = tid & 31, ty = tid >> 5;  // 32 x 8
        int k0 = by * 32, n0 = bx * 32;
        const float* Wg = z ? Wg_b : Wg_a;
        unsigned short* o = wT + (size_t)z * FF * FF;
#pragma unroll
        for (int r = 0; r < 4; ++r) {
            int row = ty + r * 8;
            tile[row][tx] = Wg[(k0 + row) * FF + n0 + tx];
        }
        __syncthreads();
#pragma unroll
        for (int r = 0; r < 4; ++r) {
            int row = ty + r * 8;
            o[(n0 + row) * FF + k0 + tx] = f2bf(tile[tx][row]);
        }
    } else {
        // in-degree count (exact multiple: no bound check)
        int i = (blk - NB_CONV - NB_WT) * 256 + tid;
        int g = i / EG, e = i - g * EG;
        const int* ei = (g < B) ? (ei_a + (size_t)g * 2 * EG)
                                : (ei_b + (size_t)(g - B) * 2 * EG);
        int t = ei[EG + e];
        atomicAdd(&degi[g * NN + t], 1);
    }
}

// per-graph exclusive scan of in-degree -> CSR offsets, cursor init, dinv
__global__ void k_scan(const int* __restrict__ degi, int* __restrict__ csr_off,
                       int* __restrict__ cursor, float* __restrict__ dinv) {
    int g = blockIdx.x, t = threadIdx.x;
    __shared__ int part[256];
    int loc[8];
    int s = 0;
#pragma unroll
    for (int i = 0; i < 8; ++i) {
        int n = t * 8 + i;
        int c = (n < NN) ? degi[g * NN + n] : 0;
        if (n < NN) dinv[g * NN + n] = rsqrtf((float)(c + 1));  // +1 self loop
        loc[i] = s;
        s += c;
    }
    part[t] = s;
    __syncthreads();
    for (int off = 1; off < 256; off <<= 1) {
        int v = (t >= off) ? part[t - off] : 0;
        __syncthreads();
        part[t] += v;
        __syncthreads();
    }
    int base = part[t] - s;
#pragma unroll
    for (int i = 0; i < 8; ++i) {
        int n = t * 8 + i;
        if (n < NN) {
            int o = base + loc[i];
            csr_off[g * (NN + 1) + n] = o;
            cursor[g * NN + n] = o;
        }
    }
    if (t == 255) csr_off[g * (NN + 1) + NN] = part[255];
}

// ---------------- fused GEMM + fillcsr ----------------
// blocks [0, NB_GEMM): bf16 MFMA GEMM (global_load_lds staging, XCD remap)
// blocks [NB_GEMM, NB_GEMM+NB_FILL): CSR fill (latency-bound, hides under MFMA)
__launch_bounds__(256) __global__
void k_gemm_fill(const unsigned short* __restrict__ Abf, const unsigned short* __restrict__ wT,
                 unsigned short* __restrict__ Hbf,
                 const int* __restrict__ ei_a, const int* __restrict__ ei_b,
                 int* __restrict__ cursor, const float* __restrict__ dinv,
                 int2* __restrict__ epk) {
    int blk = blockIdx.x;
    __shared__ __align__(16) unsigned short As[128 * BK];
    __shared__ __align__(16) unsigned short Bs[128 * BK];
    if (blk >= NB_GEMM) {
        // ---- fillcsr ----
        int i = (blk - NB_GEMM) * 256 + threadIdx.x;
        int g = i / EG, e = i - g * EG;
        const int* ei = (g < B) ? (ei_a + (size_t)g * 2 * EG)
                                : (ei_b + (size_t)(g - B) * 2 * EG);
        int s = ei[e];
        int t = ei[EG + e];
        int pos = atomicAdd(&cursor[g * NN + t], 1);
        int2 p;
        p.x = s;
        p.y = __float_as_int(dinv[g * NN + s] * dinv[g * NN + t]);
        epk[(size_t)g * EG + pos] = p;
        return;
    }
    // ---- GEMM: blk bits [2:0]=XCD slot (m-tile low), [5:3]=n-tile, [10:6]=m-group
    int mt = ((blk >> 6) << 3) | (blk & 7);
    int nt = (blk >> 3) & 7;
    if (mt >= 250) return;
    int m0 = mt * 128, n0 = nt * 128;
    const unsigned short* Bbf = (mt >= 125) ? (wT + (size_t)FF * FF) : wT;

    int tid = threadIdx.x;
    int lane = tid & 63, wave = tid >> 6;
    int wr = wave >> 1, wc = wave & 1;
    int q = lane >> 4, l15 = lane & 15;
    int lr = lane >> 2, lc = lane & 3;

    f32x4 acc[4][4];
#pragma unroll
    for (int i = 0; i < 4; ++i)
#pragma unroll
        for (int j = 0; j < 4; ++j) acc[i][j] = (f32x4){0.f, 0.f, 0.f, 0.f};

    for (int kt = 0; kt < 32; ++kt) {
        int kb = kt * BK;
#pragma unroll
        for (int p = 0; p < 2; ++p) {
            int rbase = p * 64 + wave * 16;      // wave-uniform
            int r = rbase + lr;                  // per-lane global row
            __builtin_amdgcn_global_load_lds(
                (const __attribute__((address_space(1))) unsigned int*)
                    &Abf[(size_t)(m0 + r) * FF + kb + lc * 8],
                (__attribute__((address_space(3))) unsigned int*)&As[rbase * BK],
                16, 0, 0);
            __builtin_amdgcn_global_load_lds(
                (const __attribute__((address_space(1))) unsigned int*)
                    &Bbf[(size_t)(n0 + r) * FF + kb + lc * 8],
                (__attribute__((address_space(3))) unsigned int*)&Bs[rbase * BK],
                16, 0, 0);
        }
        __syncthreads();
        short8 fa[4], fb[4];
#pragma unroll
        for (int i = 0; i < 4; ++i)
            fa[i] = *(const short8*)&As[(wr * 64 + i * 16 + l15) * BK + q * 8];
#pragma unroll
        for (int j = 0; j < 4; ++j)
            fb[j] = *(const short8*)&Bs[(wc * 64 + j * 16 + l15) * BK + q * 8];
#pragma unroll
        for (int i = 0; i < 4; ++i)
#pragma unroll
            for (int j = 0; j < 4; ++j)
                acc[i][j] = __builtin_amdgcn_mfma_f32_16x16x32_bf16(fa[i], fb[j], acc[i][j], 0, 0, 0);
        __syncthreads();
    }
#pragma unroll
    for (int i = 0; i < 4; ++i) {
#pragma unroll
        for (int j = 0; j < 4; ++j) {
            int n = n0 + wc * 64 + j * 16 + l15;
#pragma unroll
            for (int v = 0; v < 4; ++v) {
                int m = m0 + wr * 64 + i * 16 + q * 4 + v;
                Hbf[(size_t)m * FF + n] = f2bf(acc[i][j][v]);
            }
        }
    }
}

// ---------------- fused aggregation + bias + leaky + node-sum ----------------
// Feature-half phasing: grid = 4*1000 blocks, phase = blk/1000.
// half = phase&1, graph-set = phase>>1. XCD = blk&7 -> per-XCD working set =
// 2.05MB H-half + 0.5MB epk < 4MB L2. f32x2 math; edge stream software-pipelined.
__launch_bounds__(256) __global__
void k_aggreduce(const unsigned short* __restrict__ Hbf, const int* __restrict__ csr_off,
                 const int2* __restrict__ epk, const float* __restrict__ dinv,
                 const float* __restrict__ bg_a, const float* __restrict__ bg_b,
                 float* __restrict__ part) {
    int blk = blockIdx.x;
    int phase = blk / 1000;
    int bp = blk - phase * 1000;
    int half = phase & 1;
    int g = (phase >> 1) * 8 + (bp & 7);
    int chunk = bp >> 3;         // 0..124
    int tid = threadIdx.x;
    int team = tid >> 6;         // 0..3
    int lane = tid & 63;
    int f0 = half * 512 + lane * 8;
    int n0 = chunk * 16 + team * 4;
    const unsigned short* Hb = Hbf + (size_t)g * NN * FF;
    const int2* ep = epk + (size_t)g * EG;
    const float* bg = (g < B) ? bg_a : bg_b;

    f32x2 bgv[4];
#pragma unroll
    for (int i = 0; i < 4; ++i) bgv[i] = (f32x2){bg[f0 + 2 * i], bg[f0 + 2 * i + 1]};
    f32x2 bsum[4];
#pragma unroll
    for (int i = 0; i < 4; ++i) bsum[i] = (f32x2){0.f, 0.f};

    for (int nn = 0; nn < 4; ++nn) {
        int n = n0 + nn;
        float dn = dinv[g * NN + n];
        int beg = csr_off[g * (NN + 1) + n];
        int end = csr_off[g * (NN + 1) + n + 1];
        f32x2 racc[4];
#pragma unroll
        for (int i = 0; i < 4; ++i) racc[i] = (f32x2){0.f, 0.f};
        {   // self-loop (weight 1/deg)
            uint4 sv = *(const uint4*)&Hb[(n << 10) + f0];
            acc8p(racc, dn * dn, sv);
        }
        int j = beg;
        int2 pe0, pe1, pe2, pe3;
        if (j + 4 <= end) { pe0 = ep[j]; pe1 = ep[j + 1]; pe2 = ep[j + 2]; pe3 = ep[j + 3]; }
        for (; j + 8 <= end; j += 4) {
            int2 e0 = pe0, e1 = pe1, e2 = pe2, e3 = pe3;
            pe0 = ep[j + 4]; pe1 = ep[j + 5]; pe2 = ep[j + 6]; pe3 = ep[j + 7];
            uint4 v0 = *(const uint4*)&Hb[(e0.x << 10) + f0];
            uint4 v1 = *(const uint4*)&Hb[(e1.x << 10) + f0];
            uint4 v2 = *(const uint4*)&Hb[(e2.x << 10) + f0];
            uint4 v3 = *(const uint4*)&Hb[(e3.x << 10) + f0];
            acc8p(racc, __int_as_float(e0.y), v0);
            acc8p(racc, __int_as_float(e1.y), v1);
            acc8p(racc, __int_as_float(e2.y), v2);
            acc8p(racc, __int_as_float(e3.y), v3);
        }
        if (j + 4 <= end) {
            uint4 v0 = *(const uint4*)&Hb[(pe0.x << 10) + f0];
            uint4 v1 = *(const uint4*)&Hb[(pe1.x << 10) + f0];
            uint4 v2 = *(const uint4*)&Hb[(pe2.x << 10) + f0];
            uint4 v3 = *(const uint4*)&Hb[(pe3.x << 10) + f0];
            acc8p(racc, __int_as_float(pe0.y), v0);
            acc8p(racc, __int_as_float(pe1.y), v1);
            acc8p(racc, __int_as_float(pe2.y), v2);
            acc8p(racc, __int_as_float(pe3.y), v3);
            j += 4;
        }
        for (; j < end; ++j) {
            int2 e = ep[j];
            uint4 v = *(const uint4*)&Hb[(e.x << 10) + f0];
            acc8p(racc, __int_as_float(e.y), v);
        }
#pragma unroll
        for (int i = 0; i < 4; ++i) {
            f32x2 t = racc[i] + bgv[i];
            bsum[i].x += leaky(t.x);
            bsum[i].y += leaky(t.y);
        }
    }

    // reduce across the 4 teams; stride-9 padding avoids bank conflicts
    __shared__ float red[3][64 * 9];
    if (team > 0) {
#pragma unroll
        for (int i = 0; i < 4; ++i) {
            red[team - 1][lane * 9 + 2 * i]     = bsum[i].x;
            red[team - 1][lane * 9 + 2 * i + 1] = bsum[i].y;
        }
    }
    __syncthreads();
    if (team == 0) {
        float* o = part + ((size_t)g * NCHUNK + chunk) * FF + f0;
        float r[8];
#pragma unroll
        for (int i = 0; i < 4; ++i) {
            r[2 * i]     = bsum[i].x;
            r[2 * i + 1] = bsum[i].y;
        }
#pragma unroll
        for (int t = 0; t < 3; ++t)
#pragma unroll
            for (int i = 0; i < 8; ++i) r[i] += red[t][lane * 9 + i];
        float4 a = {r[0], r[1], r[2], r[3]};
        float4 c = {r[4], r[5], r[6], r[7]};
        *(float4*)&o[0] = a;
        *(float4*)&o[4] = c;
    }
}

// tree level 1: sum 25 chunks -> part2[g][cg][f]
__global__ void k_gsum1(const float* __restrict__ part, float* __restrict__ part2) {
    int blk = blockIdx.x;               // g*20 + fq*5 + cg
    int g = blk / 20;
    int rem = blk - g * 20;
    int fq = rem / CG, cg = rem - fq * CG;
    int f = fq * 256 + threadIdx.x;
    const float* p = part + (size_t)g * NCHUNK * FF + (size_t)cg * 25 * FF + f;
    float s = 0.f;
#pragma unroll 5
    for (int c = 0; c < 25; ++c) s += p[(size_t)c * FF];
    part2[((size_t)g * CG + cg) * FF + f] = s;
}

// fc: sum 5 partials in LDS + GEMV + leaky
__global__ void k_fc(const float* __restrict__ part2, const float* __restrict__ Wf_a,
                     const float* __restrict__ bf_a, const float* __restrict__ Wf_b,
                     const float* __restrict__ bf_b, float* __restrict__ g12) {
    int g = blockIdx.x, d = threadIdx.x;  // 128 threads
    __shared__ float gs[FF];
    const float* p = part2 + (size_t)g * CG * FF;
#pragma unroll
    for (int i = 0; i < 8; ++i) {
        int f = i * 128 + d;
        float s = 0.f;
#pragma unroll
        for (int c = 0; c < CG; ++c) s += p[(size_t)c * FF + f];
        gs[f] = s;
    }
    __syncthreads();
    const float* Wf = (g < B) ? Wf_a : Wf_b;
    const float* bfv = (g < B) ? bf_a : bf_b;
    float acc = 0.f;
#pragma unroll 8
    for (int f = 0; f < FF; ++f) acc += gs[f] * Wf[f * DD + d];
    acc = acc * (1.0f / (float)NN) + bfv[d];
    g12[g * DD + d] = leaky(acc);
}

__launch_bounds__(256) __global__
void k_head(const float* __restrict__ g, const float* __restrict__ W1, const float* __restrict__ b1,
            const float* __restrict__ W2, const float* __restrict__ b2,
            const float* __restrict__ Wo, const float* __restrict__ bo, float* __restrict__ out) {
    __shared__ float xc[8][256];
    __shared__ float l1[8][256];
    __shared__ float l2[8][64];
    int t = threadIdx.x;
#pragma unroll
    for (int i = 0; i < 8; ++i) {
        int idx = i * 256 + t;
        int b = idx >> 8, j = idx & 255;
        xc[b][j] = (j < DD) ? g[b * DD + j] : g[B * DD + b * DD + (j - DD)];
    }
    __syncthreads();
    {
        int j = t;
        float a[8];
#pragma unroll
        for (int b = 0; b < 8; ++b) a[b] = b1[j];
        for (int k = 0; k < 256; ++k) {
            float w = W1[k * 256 + j];
#pragma unroll
            for (int b = 0; b < 8; ++b) a[b] += xc[b][k] * w;
        }
#pragma unroll
        for (int b = 0; b < 8; ++b) l1[b][j] = leaky(a[b]);
    }
    __syncthreads();
    if (t < 64) {
        int j = t;
        float a[8];
#pragma unroll
        for (int b = 0; b < 8; ++b) a[b] = b2[j];
        for (int k = 0; k < 256; ++k) {
            float w = W2[k * 64 + j];
#pragma unroll
            for (int b = 0; b < 8; ++b) a[b] += l1[b][k] * w;
        }
#pragma unroll
        for (int b = 0; b < 8; ++b) l2[b][j] = leaky(a[b]);
    }
    __syncthreads();
    if (t < 8) {
        float a = bo[0];
        for (int k = 0; k < 64; ++k) a += l2[t][k] * Wo[k];
        out[t] = 1.0f / (1.0f + expf(-a));
    }
}

extern "C" void kernel_launch(void* const* d_in, const int* in_sizes, int n_in,
                              void* d_out, int out_size, void* d_ws, size_t ws_size,
                              hipStream_t stream) {
    const float* x1  = (const float*)d_in[0];
    const int*   ei1 = (const int*)d_in[1];
    const float* x2  = (const float*)d_in[2];
    const int*   ei2 = (const int*)d_in[3];
    const float* Wg1 = (const float*)d_in[4];
    const float* bg1 = (const float*)d_in[5];
    const float* Wf1 = (const float*)d_in[6];
    const float* bf1 = (const float*)d_in[7];
    const float* Wg2 = (const float*)d_in[8];
    const float* bg2 = (const float*)d_in[9];
    const float* Wf2 = (const float*)d_in[10];
    const float* bf2 = (const float*)d_in[11];
    const float* W1  = (const float*)d_in[12];
    const float* b1  = (const float*)d_in[13];
    const float* W2  = (const float*)d_in[14];
    const float* b2  = (const float*)d_in[15];
    const float* Wo  = (const float*)d_in[16];
    const float* bo  = (const float*)d_in[17];
    float* out = (float*)d_out;

    // ---- batched (NG=16) workspace layout ----
    auto align = [](size_t v) { return (v + 255) & ~(size_t)255; };
    size_t need = 0;
    size_t o_deg  = need; need += align((size_t)16 * NN * 4);
    size_t o_dinv = need; need += align((size_t)16 * NN * 4);
    size_t o_csr  = need; need += align((size_t)16 * (NN + 1) * 4);
    size_t o_cur  = need; need += align((size_t)16 * NN * 4);
    size_t o_epk  = need; need += align((size_t)16 * EG * 8);
    size_t o_xbf  = need; need += align((size_t)16 * NN * FF * 2);
    size_t o_wT   = need; need += align((size_t)2 * FF * FF * 2);
    size_t o_hbf  = need; need += align((size_t)16 * NN * FF * 2);
    size_t o_part = need; need += align((size_t)16 * NCHUNK * FF * 4);
    size_t o_pt2  = need; need += align((size_t)16 * CG * FF * 4);
    size_t o_g12  = need; need += align((size_t)16 * DD * 4);
    (void)need;  // ws_size has been >= need (~152 MB) every round; batched path only

    char* w = (char*)d_ws;
    int* degi    = (int*)(w + o_deg);
    float* dinv  = (float*)(w + o_dinv);
    int* csr     = (int*)(w + o_csr);
    int* cur     = (int*)(w + o_cur);
    int2* epk    = (int2*)(w + o_epk);
    unsigned short* xbf = (unsigned short*)(w + o_xbf);
    unsigned short* wT  = (unsigned short*)(w + o_wT);
    unsigned short* hbf = (unsigned short*)(w + o_hbf);
    float* part  = (float*)(w + o_part);
    float* part2 = (float*)(w + o_pt2);
    float* g12   = (float*)(w + o_g12);

    // 8 nodes total: memset + 7 kernels
    hipMemsetAsync(degi, 0, (size_t)16 * NN * 4, stream);
    k_prep<<<NB_CONV + NB_WT + NB_DEG, 256, 0, stream>>>(x1, x2, xbf, Wg1, Wg2, wT,
                                                         ei1, ei2, degi);
    k_scan<<<16, 256, 0, stream>>>(degi, csr, cur, dinv);
    k_gemm_fill<<<NB_GEMM + NB_FILL, 256, 0, stream>>>(xbf, wT, hbf, ei1, ei2, cur,
                                                       dinv, epk);
    k_aggreduce<<<4000, 256, 0, stream>>>(hbf, csr, epk, dinv, bg1, bg2, part);
    k_gsum1<<<16 * 20, 256, 0, stream>>>(part, part2);
    k_fc<<<16, DD, 0, stream>>>(part2, Wf1, bf1, Wf2, bf2, g12);
    k_head<<<1, 256, 0, stream>>>(g12, W1, b1, W2, b2, Wo, bo, out);
}